// Round 6
// baseline (332.152 us; speedup 1.0000x reference)
//
#include <hip/hip_runtime.h>
#include <hip/hip_bf16.h>

// ---- degree histogram: deg[dst] += 1 per edge ----
__global__ void deg_kernel(const int* __restrict__ dst, float* __restrict__ deg, int E) {
    int e = blockIdx.x * blockDim.x + threadIdx.x;
    if (e < E) atomicAdd(&deg[dst[e]], 1.0f);
}

// ---- dis = deg > 0 ? deg^-0.5 : 0 (in-place) ----
__global__ void dis_kernel(float* __restrict__ deg, int n) {
    int i = blockIdx.x * blockDim.x + threadIdx.x;
    if (i < n) {
        float d = deg[i];
        deg[i] = (d > 0.0f) ? rsqrtf(d) : 0.0f;
    }
}

// ---- hierarchical scan pass A: per-block inclusive scan + block sums ----
__global__ __launch_bounds__(256) void scanA_kernel(const float* __restrict__ deg,
                                                    int* __restrict__ rowptr,
                                                    int* __restrict__ bsum, int n) {
    __shared__ int lds[256];
    int i = blockIdx.x * 256 + threadIdx.x;
    int v = (i < n) ? (int)deg[i] : 0;
    lds[threadIdx.x] = v;
    __syncthreads();
    #pragma unroll
    for (int off = 1; off < 256; off <<= 1) {
        int t = (threadIdx.x >= off) ? lds[threadIdx.x - off] : 0;
        __syncthreads();
        lds[threadIdx.x] += t;
        __syncthreads();
    }
    if (i < n) rowptr[i + 1] = lds[threadIdx.x];
    if (threadIdx.x == 255) bsum[blockIdx.x] = lds[255];
}

// ---- pass B: single-block exclusive scan of block sums (nb <= 1024) ----
__global__ __launch_bounds__(1024) void scanB_kernel(int* __restrict__ bsum, int nb) {
    __shared__ int lds[1024];
    int t = threadIdx.x;
    int v = (t < nb) ? bsum[t] : 0;
    lds[t] = v;
    __syncthreads();
    #pragma unroll
    for (int off = 1; off < 1024; off <<= 1) {
        int u = (t >= off) ? lds[t - off] : 0;
        __syncthreads();
        lds[t] += u;
        __syncthreads();
    }
    if (t < nb) bsum[t] = lds[t] - v;   // inclusive - self = exclusive
}

// ---- pass C: add block offsets ----
__global__ __launch_bounds__(256) void scanC_kernel(int* __restrict__ rowptr,
                                                    const int* __restrict__ bsum, int n) {
    int i = blockIdx.x * 256 + threadIdx.x;
    if (i < n) rowptr[i + 1] += bsum[blockIdx.x];
    if (i == 0) rowptr[0] = 0;
}

// ---- fallback single-block scan (only if n > 262144) ----
__global__ __launch_bounds__(1024) void scan_kernel(const float* __restrict__ deg,
                                                    int* __restrict__ rowptr, int n) {
    __shared__ int part[1024];
    int tid = threadIdx.x;
    int chunk = (n + 1023) / 1024;
    int beg = tid * chunk;
    int end = beg + chunk; if (end > n) end = n;
    int s = 0;
    for (int i = beg; i < end; ++i) s += (int)deg[i];
    part[tid] = s;
    __syncthreads();
    for (int off = 1; off < 1024; off <<= 1) {
        int v = (tid >= off) ? part[tid - off] : 0;
        __syncthreads();
        part[tid] += v;
        __syncthreads();
    }
    int run = (tid > 0) ? part[tid - 1] : 0;
    if (tid == 0) rowptr[0] = 0;
    for (int i = beg; i < end; ++i) { run += (int)deg[i]; rowptr[i + 1] = run; }
}

// ---- scatter edges into CSR: ecolw[pos] = {src_bits, dis[src]*dis[dst]} ----
__global__ void scatter_kernel(const int* __restrict__ src, const int* __restrict__ dst,
                               const float* __restrict__ dis, const int* __restrict__ rowptr,
                               int* __restrict__ cnt, float2* __restrict__ ecolw, int E) {
    int e = blockIdx.x * blockDim.x + threadIdx.x;
    if (e < E) {
        int s = src[e], d = dst[e];
        int pos = atomicAdd(&cnt[d], 1);
        ecolw[rowptr[d] + pos] = make_float2(__int_as_float(s), dis[s] * dis[d]);
    }
}

// ---- GEMM1: z_k = rownorm(x) @ W1[k].  rownorm commutes: (x/S)W = (xW)/S ----
// One wave per row (x wave-uniform); lane's W column MUST stay in 128 VGPRs.
// R4/R5 evidence: compiler sank the W loads into the row loop (VGPR=80, ~1.6 GB
// L2 re-read, 60us). The empty-asm "+v" pin makes each wr[d] an opaque VGPR
// value the scheduler cannot rematerialize or sink. launch_bounds(256,2) caps
// VGPR at 256 (~170 needed).
__global__ __launch_bounds__(256, 2) void gemm1_kernel(
    const float* __restrict__ x, const float* __restrict__ W1,
    float* __restrict__ z, int n, int nstride)
{
    int lane = threadIdx.x & 63;
    int k = lane >> 4, oo = lane & 15;
    float wr[128];
    #pragma unroll
    for (int d = 0; d < 128; ++d)
        wr[d] = W1[k * 2048 + d * 16 + oo];     // W1[k][d][oo]
    #pragma unroll
    for (int d = 0; d < 128; ++d)
        asm volatile("" : "+v"(wr[d]));         // pin in VGPRs — no sinking/remat
    int wid = blockIdx.x * (blockDim.x >> 6) + (threadIdx.x >> 6);
    int nw  = gridDim.x * (blockDim.x >> 6);
    for (int row = wid; row < n; row += nw) {
        int urow = __builtin_amdgcn_readfirstlane(row);
        const float4* xr = (const float4*)(x + (long)urow * 128);
        float acc0 = 0.f, acc1 = 0.f, sum0 = 0.f, sum1 = 0.f;
        #pragma unroll
        for (int j = 0; j < 32; j += 2) {
            float4 a = xr[j], b = xr[j + 1];
            acc0 += a.x * wr[4*j+0] + a.y * wr[4*j+1] + a.z * wr[4*j+2] + a.w * wr[4*j+3];
            acc1 += b.x * wr[4*j+4] + b.y * wr[4*j+5] + b.z * wr[4*j+6] + b.w * wr[4*j+7];
            sum0 += (a.x + a.y) + (a.z + a.w);
            sum1 += (b.x + b.y) + (b.z + b.w);
        }
        float scale = 1.0f / fmaxf(sum0 + sum1, 1e-8f);
        z[(long)k * nstride + (long)urow * 16 + oo] = (acc0 + acc1) * scale;
    }
}

// ---- CSR SpMM (width 16): out[r,:] = sum_e w[e]*in[col[e],:] (+addsrc)(+b)(relu) ----
__global__ __launch_bounds__(256) void spmm_csr_kernel(
    const float* __restrict__ in, const float* __restrict__ addsrc,
    float* __restrict__ out, const int* __restrict__ rowptr,
    const float2* __restrict__ ecolw, const float* __restrict__ b,
    int relu, int n)
{
    int t = blockIdx.x * blockDim.x + threadIdx.x;
    int r = t >> 4, f = t & 15;
    if (r >= n) return;
    int e0 = rowptr[r], e1 = rowptr[r + 1];
    float acc0 = 0.f, acc1 = 0.f, acc2 = 0.f, acc3 = 0.f;
    int e = e0;
    for (; e + 4 <= e1; e += 4) {
        float2 c0 = ecolw[e], c1 = ecolw[e + 1], c2 = ecolw[e + 2], c3 = ecolw[e + 3];
        acc0 += c0.y * in[__float_as_int(c0.x) * 16 + f];
        acc1 += c1.y * in[__float_as_int(c1.x) * 16 + f];
        acc2 += c2.y * in[__float_as_int(c2.x) * 16 + f];
        acc3 += c3.y * in[__float_as_int(c3.x) * 16 + f];
    }
    for (; e < e1; ++e) {
        float2 c0 = ecolw[e];
        acc0 += c0.y * in[__float_as_int(c0.x) * 16 + f];
    }
    float acc = (acc0 + acc1) + (acc2 + acc3);
    if (addsrc) acc += addsrc[r * 16 + f];
    if (b)      acc += b[f];
    if (relu)   acc = fmaxf(acc, 0.f);
    out[r * 16 + f] = acc;
}

// ---- GEMM2: out[n,64] = cat(planes) @ W2cat + b2, scalar-broadcast scheme ----
__global__ __launch_bounds__(256, 2) void gemm2_kernel(
    const float* __restrict__ z, const float* __restrict__ W2,
    const float* __restrict__ b2, float* __restrict__ out, int n, int nstride)
{
    int lane = threadIdx.x & 63;
    float wr[64];
    #pragma unroll
    for (int j = 0; j < 64; ++j) wr[j] = W2[j * 64 + lane];
    #pragma unroll
    for (int j = 0; j < 64; ++j)
        asm volatile("" : "+v"(wr[j]));         // pin in VGPRs
    float bias = b2[lane];
    int wid = blockIdx.x * (blockDim.x >> 6) + (threadIdx.x >> 6);
    int nw  = gridDim.x * (blockDim.x >> 6);
    for (int row = wid; row < n; row += nw) {
        int urow = __builtin_amdgcn_readfirstlane(row);
        float acc0 = 0.f, acc1 = 0.f;
        #pragma unroll
        for (int p = 0; p < 4; ++p) {
            const float4* zr = (const float4*)(z + (long)p * nstride + (long)urow * 16);
            float4 a = zr[0], bb = zr[1], c = zr[2], d = zr[3];
            acc0 += a.x  * wr[p*16+ 0] + a.y  * wr[p*16+ 1] + a.z  * wr[p*16+ 2] + a.w  * wr[p*16+ 3];
            acc1 += bb.x * wr[p*16+ 4] + bb.y * wr[p*16+ 5] + bb.z * wr[p*16+ 6] + bb.w * wr[p*16+ 7];
            acc0 += c.x  * wr[p*16+ 8] + c.y  * wr[p*16+ 9] + c.z  * wr[p*16+10] + c.w  * wr[p*16+11];
            acc1 += d.x  * wr[p*16+12] + d.y  * wr[p*16+13] + d.z  * wr[p*16+14] + d.w  * wr[p*16+15];
        }
        out[(long)urow * 64 + lane] = acc0 + acc1 + bias;
    }
}

// ---- fallback: edge-parallel atomic SpMM with on-the-fly norm ----
__global__ __launch_bounds__(256) void spmm_atomic_kernel(
    const float* __restrict__ in, float* __restrict__ out,
    const int* __restrict__ src, const int* __restrict__ dst,
    const float* __restrict__ dis, int E)
{
    int t = blockIdx.x * blockDim.x + threadIdx.x;
    int e = t >> 4, f = t & 15;
    if (e < E) {
        int s = src[e], d = dst[e];
        atomicAdd(&out[d * 16 + f], dis[s] * dis[d] * in[s * 16 + f]);
    }
}

__global__ void bias_relu_kernel(float* __restrict__ z0, const float* __restrict__ b, int total) {
    int i = blockIdx.x * blockDim.x + threadIdx.x;
    if (i < total) {
        float v = z0[i] + b[i & 15];
        z0[i] = v > 0.0f ? v : 0.0f;
    }
}

extern "C" void kernel_launch(void* const* d_in, const int* in_sizes, int n_in,
                              void* d_out, int out_size, void* d_ws, size_t ws_size,
                              hipStream_t stream) {
    const float* x   = (const float*)d_in[0];
    const int*   ei  = (const int*)d_in[1];
    const float* W1  = (const float*)d_in[2];
    const float* b1  = (const float*)d_in[3];
    const float* W2  = (const float*)d_in[4];
    const float* bb2 = (const float*)d_in[5];
    float* out = (float*)d_out;

    const int n  = in_sizes[0] / 128;   // 50000
    const int E  = in_sizes[1] / 2;     // 800000
    const int NS = n * 16;

    const int* srcp = ei;
    const int* dstp = ei + E;

    float* ws = (float*)d_ws;
    // layout: deg/dis [n] | rowptr [n+1] | cnt [n] | bsum [1024] | (pad) | z [4*NS] | ecolw [2*E]
    float* deg    = ws;
    int*   rowptr = (int*)(ws + n);
    int*   cnt    = (int*)(ws + 2 * n + 1);
    int*   bsum   = (int*)(ws + 3 * n + 1);
    size_t zoff   = ((size_t)(3 * n + 1 + 1024) + 3) & ~(size_t)3;   // 16B align
    float* z      = ws + zoff;
    float2* ecolw = (float2*)(z + 4 * (size_t)NS);
    size_t need   = (zoff + 4 * (size_t)NS + 2 * (size_t)E) * sizeof(float);

    if (ws_size >= need) {
        // ---------- CSR path ----------
        int nb = (n + 255) / 256;
        hipMemsetAsync(ws, 0, (size_t)(3 * n + 1 + 1024) * sizeof(float), stream);
        deg_kernel<<<(E + 255) / 256, 256, 0, stream>>>(dstp, deg, E);
        if (nb <= 1024) {
            scanA_kernel<<<nb, 256, 0, stream>>>(deg, rowptr, bsum, n);
            scanB_kernel<<<1, 1024, 0, stream>>>(bsum, nb);
            scanC_kernel<<<nb, 256, 0, stream>>>(rowptr, bsum, n);
        } else {
            scan_kernel<<<1, 1024, 0, stream>>>(deg, rowptr, n);
        }
        dis_kernel<<<(n + 255) / 256, 256, 0, stream>>>(deg, n);   // deg -> dis in place
        scatter_kernel<<<(E + 255) / 256, 256, 0, stream>>>(srcp, dstp, deg, rowptr, cnt, ecolw, E);

        gemm1_kernel<<<2048, 256, 0, stream>>>(x, W1, z, n, NS);

        int sb = (16 * n + 255) / 256;
        // Horner layer 1
        spmm_csr_kernel<<<sb, 256, 0, stream>>>(z + 3 * NS, z + 2 * NS, z + 2 * NS, rowptr, ecolw, nullptr, 0, n);
        spmm_csr_kernel<<<sb, 256, 0, stream>>>(z + 2 * NS, z + 1 * NS, z + 1 * NS, rowptr, ecolw, nullptr, 0, n);
        spmm_csr_kernel<<<sb, 256, 0, stream>>>(z + 1 * NS, z,          z,          rowptr, ecolw, b1,      1, n);
        // layer 2 hops
        spmm_csr_kernel<<<sb, 256, 0, stream>>>(z,          nullptr, z + 1 * NS, rowptr, ecolw, nullptr, 0, n);
        spmm_csr_kernel<<<sb, 256, 0, stream>>>(z + 1 * NS, nullptr, z + 2 * NS, rowptr, ecolw, nullptr, 0, n);
        spmm_csr_kernel<<<sb, 256, 0, stream>>>(z + 2 * NS, nullptr, z + 3 * NS, rowptr, ecolw, nullptr, 0, n);

        gemm2_kernel<<<1024, 256, 0, stream>>>(z, W2, bb2, out, n, NS);
    } else {
        // ---------- fallback: atomic path (dis [n] | z [4*NS]) ----------
        float* dis2 = ws;
        size_t z2off = ((size_t)n + 3) & ~(size_t)3;
        float* z2 = ws + z2off;
        hipMemsetAsync(dis2, 0, n * sizeof(float), stream);
        deg_kernel<<<(E + 255) / 256, 256, 0, stream>>>(dstp, dis2, E);
        dis_kernel<<<(n + 255) / 256, 256, 0, stream>>>(dis2, n);
        gemm1_kernel<<<2048, 256, 0, stream>>>(x, W1, z2, n, NS);
        int sb = (16 * E + 255) / 256;
        spmm_atomic_kernel<<<sb, 256, 0, stream>>>(z2 + 3 * NS, z2 + 2 * NS, srcp, dstp, dis2, E);
        spmm_atomic_kernel<<<sb, 256, 0, stream>>>(z2 + 2 * NS, z2 + 1 * NS, srcp, dstp, dis2, E);
        spmm_atomic_kernel<<<sb, 256, 0, stream>>>(z2 + 1 * NS, z2,          srcp, dstp, dis2, E);
        bias_relu_kernel<<<(NS + 255) / 256, 256, 0, stream>>>(z2, b1, NS);
        hipMemsetAsync(z2 + NS, 0, (size_t)3 * NS * sizeof(float), stream);
        spmm_atomic_kernel<<<sb, 256, 0, stream>>>(z2,          z2 + NS,     srcp, dstp, dis2, E);
        spmm_atomic_kernel<<<sb, 256, 0, stream>>>(z2 + NS,     z2 + 2 * NS, srcp, dstp, dis2, E);
        spmm_atomic_kernel<<<sb, 256, 0, stream>>>(z2 + 2 * NS, z2 + 3 * NS, srcp, dstp, dis2, E);
        gemm2_kernel<<<1024, 256, 0, stream>>>(z2, W2, bb2, out, n, NS);
    }
}

// Round 7
// 293.071 us; speedup vs baseline: 1.1334x; 1.1334x over previous
//
#include <hip/hip_runtime.h>
#include <hip/hip_bf16.h>

// ---- degree histogram: deg[dst] += 1 per edge ----
__global__ void deg_kernel(const int* __restrict__ dst, float* __restrict__ deg, int E) {
    int e = blockIdx.x * blockDim.x + threadIdx.x;
    if (e < E) atomicAdd(&deg[dst[e]], 1.0f);
}

// ---- dis = deg > 0 ? deg^-0.5 : 0 (in-place) ----
__global__ void dis_kernel(float* __restrict__ deg, int n) {
    int i = blockIdx.x * blockDim.x + threadIdx.x;
    if (i < n) {
        float d = deg[i];
        deg[i] = (d > 0.0f) ? rsqrtf(d) : 0.0f;
    }
}

// ---- hierarchical scan pass A ----
__global__ __launch_bounds__(256) void scanA_kernel(const float* __restrict__ deg,
                                                    int* __restrict__ rowptr,
                                                    int* __restrict__ bsum, int n) {
    __shared__ int lds[256];
    int i = blockIdx.x * 256 + threadIdx.x;
    int v = (i < n) ? (int)deg[i] : 0;
    lds[threadIdx.x] = v;
    __syncthreads();
    #pragma unroll
    for (int off = 1; off < 256; off <<= 1) {
        int t = (threadIdx.x >= off) ? lds[threadIdx.x - off] : 0;
        __syncthreads();
        lds[threadIdx.x] += t;
        __syncthreads();
    }
    if (i < n) rowptr[i + 1] = lds[threadIdx.x];
    if (threadIdx.x == 255) bsum[blockIdx.x] = lds[255];
}

// ---- pass B: single-block exclusive scan of block sums (nb <= 1024) ----
__global__ __launch_bounds__(1024) void scanB_kernel(int* __restrict__ bsum, int nb) {
    __shared__ int lds[1024];
    int t = threadIdx.x;
    int v = (t < nb) ? bsum[t] : 0;
    lds[t] = v;
    __syncthreads();
    #pragma unroll
    for (int off = 1; off < 1024; off <<= 1) {
        int u = (t >= off) ? lds[t - off] : 0;
        __syncthreads();
        lds[t] += u;
        __syncthreads();
    }
    if (t < nb) bsum[t] = lds[t] - v;
}

// ---- pass C: add block offsets ----
__global__ __launch_bounds__(256) void scanC_kernel(int* __restrict__ rowptr,
                                                    const int* __restrict__ bsum, int n) {
    int i = blockIdx.x * 256 + threadIdx.x;
    if (i < n) rowptr[i + 1] += bsum[blockIdx.x];
    if (i == 0) rowptr[0] = 0;
}

// ---- fallback single-block scan ----
__global__ __launch_bounds__(1024) void scan_kernel(const float* __restrict__ deg,
                                                    int* __restrict__ rowptr, int n) {
    __shared__ int part[1024];
    int tid = threadIdx.x;
    int chunk = (n + 1023) / 1024;
    int beg = tid * chunk;
    int end = beg + chunk; if (end > n) end = n;
    int s = 0;
    for (int i = beg; i < end; ++i) s += (int)deg[i];
    part[tid] = s;
    __syncthreads();
    for (int off = 1; off < 1024; off <<= 1) {
        int v = (tid >= off) ? part[tid - off] : 0;
        __syncthreads();
        part[tid] += v;
        __syncthreads();
    }
    int run = (tid > 0) ? part[tid - 1] : 0;
    if (tid == 0) rowptr[0] = 0;
    for (int i = beg; i < end; ++i) { run += (int)deg[i]; rowptr[i + 1] = run; }
}

// ---- scatter edges into CSR ----
__global__ void scatter_kernel(const int* __restrict__ src, const int* __restrict__ dst,
                               const float* __restrict__ dis, const int* __restrict__ rowptr,
                               int* __restrict__ cnt, float2* __restrict__ ecolw, int E) {
    int e = blockIdx.x * blockDim.x + threadIdx.x;
    if (e < E) {
        int s = src[e], d = dst[e];
        int pos = atomicAdd(&cnt[d], 1);
        ecolw[rowptr[d] + pos] = make_float2(__int_as_float(s), dis[s] * dis[d]);
    }
}

// ---- GEMM1 (tiled): z_k = rownorm(x) @ W1[k]. BM=128, BN=64, K=2x64 slabs.
// R4-R6 evidence: per-lane W-in-128-VGPRs is un-achievable (allocator spills at 80).
// Classic LDS tiling instead: 8x4 register micro-tile per thread, As stride 132
// (4-float aligned, 2-way banks = free), rownorm folded via staged row sums.
__global__ __launch_bounds__(256) void gemm1_kernel(
    const float* __restrict__ x, const float* __restrict__ W1,
    float* __restrict__ z, int n, int nstride)
{
    __shared__ float As[64 * 132];      // [kk][row]
    __shared__ float Bs[64 * 64];       // [kk][col]
    __shared__ float sums[128];
    const int t  = threadIdx.x;
    const int tx = t & 15;              // cols 4tx..4tx+3
    const int ty = t >> 4;              // rows 8ty..8ty+7
    const int c  = t & 15;
    const int g  = t >> 4;
    const int block_row = blockIdx.x * 128;

    float acc[8][4];
    #pragma unroll
    for (int i = 0; i < 8; ++i)
        #pragma unroll
        for (int j = 0; j < 4; ++j) acc[i][j] = 0.f;

    for (int kp = 0; kp < 2; ++kp) {
        // stage A transposed (+ row-sum partials via 16-lane shfl reduce)
        #pragma unroll
        for (int i = 0; i < 8; ++i) {
            int row  = g + 16 * i;
            int grow = block_row + row;
            float v0 = 0.f, v1 = 0.f, v2 = 0.f, v3 = 0.f;
            if (grow < n) {
                const float* xp = x + (long)grow * 128 + kp * 64 + c;
                v0 = xp[0]; v1 = xp[16]; v2 = xp[32]; v3 = xp[48];
            }
            As[(c +  0) * 132 + row] = v0;
            As[(c + 16) * 132 + row] = v1;
            As[(c + 32) * 132 + row] = v2;
            As[(c + 48) * 132 + row] = v3;
            float red = (v0 + v1) + (v2 + v3);
            #pragma unroll
            for (int off = 8; off > 0; off >>= 1) red += __shfl_down(red, off, 16);
            if (c == 0) { if (kp == 0) sums[row] = red; else sums[row] += red; }
        }
        // stage B: Bs[kk][col], col=k*16+oo -> W1[(col>>4)*2048 + kglob*16 + (col&15)]
        #pragma unroll
        for (int i2 = 0; i2 < 4; ++i2) {
            int kk = g + 16 * i2;
            int kglob = kp * 64 + kk;
            float4 wv = *(const float4*)(W1 + (c >> 2) * 2048 + kglob * 16 + 4 * (c & 3));
            *(float4*)(Bs + kk * 64 + 4 * c) = wv;
        }
        __syncthreads();
        #pragma unroll 4
        for (int kk = 0; kk < 64; ++kk) {
            float4 a0 = *(const float4*)(As + kk * 132 + 8 * ty);
            float4 a1 = *(const float4*)(As + kk * 132 + 8 * ty + 4);
            float4 bv = *(const float4*)(Bs + kk * 64 + 4 * tx);
            float ar[8] = {a0.x, a0.y, a0.z, a0.w, a1.x, a1.y, a1.z, a1.w};
            float br[4] = {bv.x, bv.y, bv.z, bv.w};
            #pragma unroll
            for (int i = 0; i < 8; ++i)
                #pragma unroll
                for (int j = 0; j < 4; ++j)
                    acc[i][j] += ar[i] * br[j];
        }
        __syncthreads();
    }
    // epilogue: scale by 1/clip(rowsum), scatter into the 4 z planes
    int plane = tx >> 2;
    int oo4   = 4 * (tx & 3);
    #pragma unroll
    for (int i = 0; i < 8; ++i) {
        int row  = 8 * ty + i;
        int grow = block_row + row;
        if (grow < n) {
            float s = 1.0f / fmaxf(sums[row], 1e-8f);
            float4 o = make_float4(acc[i][0] * s, acc[i][1] * s, acc[i][2] * s, acc[i][3] * s);
            *(float4*)(z + (long)plane * nstride + (long)grow * 16 + oo4) = o;
        }
    }
}

// ---- GEMM2 (tiled): out = cat(G0..G3) @ W2cat + b2. BM=128, BN=64, K=64. ----
__global__ __launch_bounds__(256) void gemm2_kernel(
    const float* __restrict__ z, const float* __restrict__ W2,
    const float* __restrict__ b2, float* __restrict__ out, int n, int nstride)
{
    __shared__ float As[64 * 132];
    __shared__ float Bs[64 * 64];
    const int t  = threadIdx.x;
    const int tx = t & 15;
    const int ty = t >> 4;
    const int c  = t & 15;
    const int g  = t >> 4;
    const int block_row = blockIdx.x * 128;

    float acc[8][4];
    #pragma unroll
    for (int i = 0; i < 8; ++i)
        #pragma unroll
        for (int j = 0; j < 4; ++j) acc[i][j] = 0.f;

    // stage A: A[row][j] = z[(j>>4)*NS + row*16 + (j&15)], j = c + 16m
    #pragma unroll
    for (int i = 0; i < 8; ++i) {
        int row  = g + 16 * i;
        int grow = block_row + row;
        float v0 = 0.f, v1 = 0.f, v2 = 0.f, v3 = 0.f;
        if (grow < n) {
            const float* zp = z + (long)grow * 16 + c;
            v0 = zp[0];
            v1 = zp[(long)nstride];
            v2 = zp[2 * (long)nstride];
            v3 = zp[3 * (long)nstride];
        }
        As[(c +  0) * 132 + row] = v0;
        As[(c + 16) * 132 + row] = v1;
        As[(c + 32) * 132 + row] = v2;
        As[(c + 48) * 132 + row] = v3;
    }
    // stage B: W2 flat [(k*16+d)][col] is already [64][64] row-major
    #pragma unroll
    for (int i2 = 0; i2 < 4; ++i2) {
        int j = g + 16 * i2;
        float4 wv = *(const float4*)(W2 + j * 64 + 4 * c);
        *(float4*)(Bs + j * 64 + 4 * c) = wv;
    }
    __syncthreads();
    #pragma unroll 4
    for (int kk = 0; kk < 64; ++kk) {
        float4 a0 = *(const float4*)(As + kk * 132 + 8 * ty);
        float4 a1 = *(const float4*)(As + kk * 132 + 8 * ty + 4);
        float4 bv = *(const float4*)(Bs + kk * 64 + 4 * tx);
        float ar[8] = {a0.x, a0.y, a0.z, a0.w, a1.x, a1.y, a1.z, a1.w};
        float br[4] = {bv.x, bv.y, bv.z, bv.w};
        #pragma unroll
        for (int i = 0; i < 8; ++i)
            #pragma unroll
            for (int j = 0; j < 4; ++j)
                acc[i][j] += ar[i] * br[j];
    }
    float4 bias = *(const float4*)(b2 + 4 * tx);
    #pragma unroll
    for (int i = 0; i < 8; ++i) {
        int grow = block_row + 8 * ty + i;
        if (grow < n) {
            float4 o = make_float4(acc[i][0] + bias.x, acc[i][1] + bias.y,
                                   acc[i][2] + bias.z, acc[i][3] + bias.w);
            *(float4*)(out + (long)grow * 64 + 4 * tx) = o;
        }
    }
}

// ---- CSR SpMM, float4: 4 threads/row, 4-deep unrolled gathers ----
__global__ __launch_bounds__(256) void spmm_csr_kernel(
    const float* __restrict__ in, const float* __restrict__ addsrc,
    float* __restrict__ out, const int* __restrict__ rowptr,
    const float2* __restrict__ ecolw, const float* __restrict__ b,
    int relu, int n)
{
    int t = blockIdx.x * blockDim.x + threadIdx.x;
    int r = t >> 2, q = t & 3;
    if (r >= n) return;
    int e0 = rowptr[r], e1 = rowptr[r + 1];
    float4 A0 = {0,0,0,0}, A1 = {0,0,0,0}, A2 = {0,0,0,0}, A3 = {0,0,0,0};
    int e = e0;
    for (; e + 4 <= e1; e += 4) {
        float2 c0 = ecolw[e], c1 = ecolw[e+1], c2 = ecolw[e+2], c3 = ecolw[e+3];
        float4 v0 = *((const float4*)(in + (long)__float_as_int(c0.x) * 16) + q);
        float4 v1 = *((const float4*)(in + (long)__float_as_int(c1.x) * 16) + q);
        float4 v2 = *((const float4*)(in + (long)__float_as_int(c2.x) * 16) + q);
        float4 v3 = *((const float4*)(in + (long)__float_as_int(c3.x) * 16) + q);
        A0.x += c0.y*v0.x; A0.y += c0.y*v0.y; A0.z += c0.y*v0.z; A0.w += c0.y*v0.w;
        A1.x += c1.y*v1.x; A1.y += c1.y*v1.y; A1.z += c1.y*v1.z; A1.w += c1.y*v1.w;
        A2.x += c2.y*v2.x; A2.y += c2.y*v2.y; A2.z += c2.y*v2.z; A2.w += c2.y*v2.w;
        A3.x += c3.y*v3.x; A3.y += c3.y*v3.y; A3.z += c3.y*v3.z; A3.w += c3.y*v3.w;
    }
    for (; e < e1; ++e) {
        float2 c0 = ecolw[e];
        float4 v0 = *((const float4*)(in + (long)__float_as_int(c0.x) * 16) + q);
        A0.x += c0.y*v0.x; A0.y += c0.y*v0.y; A0.z += c0.y*v0.z; A0.w += c0.y*v0.w;
    }
    float4 A = make_float4((A0.x+A1.x)+(A2.x+A3.x), (A0.y+A1.y)+(A2.y+A3.y),
                           (A0.z+A1.z)+(A2.z+A3.z), (A0.w+A1.w)+(A2.w+A3.w));
    if (addsrc) {
        float4 s = *((const float4*)(addsrc + (long)r * 16) + q);
        A.x += s.x; A.y += s.y; A.z += s.z; A.w += s.w;
    }
    if (b) {
        float4 bb = *((const float4*)b + q);
        A.x += bb.x; A.y += bb.y; A.z += bb.z; A.w += bb.w;
    }
    if (relu) {
        A.x = fmaxf(A.x, 0.f); A.y = fmaxf(A.y, 0.f);
        A.z = fmaxf(A.z, 0.f); A.w = fmaxf(A.w, 0.f);
    }
    *((float4*)(out + (long)r * 16) + q) = A;
}

// ---- fallback: edge-parallel atomic SpMM ----
__global__ __launch_bounds__(256) void spmm_atomic_kernel(
    const float* __restrict__ in, float* __restrict__ out,
    const int* __restrict__ src, const int* __restrict__ dst,
    const float* __restrict__ dis, int E)
{
    int t = blockIdx.x * blockDim.x + threadIdx.x;
    int e = t >> 4, f = t & 15;
    if (e < E) {
        int s = src[e], d = dst[e];
        atomicAdd(&out[d * 16 + f], dis[s] * dis[d] * in[s * 16 + f]);
    }
}

__global__ void bias_relu_kernel(float* __restrict__ z0, const float* __restrict__ b, int total) {
    int i = blockIdx.x * blockDim.x + threadIdx.x;
    if (i < total) {
        float v = z0[i] + b[i & 15];
        z0[i] = v > 0.0f ? v : 0.0f;
    }
}

extern "C" void kernel_launch(void* const* d_in, const int* in_sizes, int n_in,
                              void* d_out, int out_size, void* d_ws, size_t ws_size,
                              hipStream_t stream) {
    const float* x   = (const float*)d_in[0];
    const int*   ei  = (const int*)d_in[1];
    const float* W1  = (const float*)d_in[2];
    const float* b1  = (const float*)d_in[3];
    const float* W2  = (const float*)d_in[4];
    const float* bb2 = (const float*)d_in[5];
    float* out = (float*)d_out;

    const int n  = in_sizes[0] / 128;   // 50000
    const int E  = in_sizes[1] / 2;     // 800000
    const int NS = n * 16;

    const int* srcp = ei;
    const int* dstp = ei + E;

    float* ws = (float*)d_ws;
    float* deg    = ws;
    int*   rowptr = (int*)(ws + n);
    int*   cnt    = (int*)(ws + 2 * n + 1);
    int*   bsum   = (int*)(ws + 3 * n + 1);
    size_t zoff   = ((size_t)(3 * n + 1 + 1024) + 3) & ~(size_t)3;
    float* z      = ws + zoff;
    float2* ecolw = (float2*)(z + 4 * (size_t)NS);
    size_t need   = (zoff + 4 * (size_t)NS + 2 * (size_t)E) * sizeof(float);

    int gemm_blocks = (n + 127) / 128;

    if (ws_size >= need) {
        // ---------- CSR path ----------
        int nb = (n + 255) / 256;
        hipMemsetAsync(ws, 0, (size_t)(3 * n + 1 + 1024) * sizeof(float), stream);
        deg_kernel<<<(E + 255) / 256, 256, 0, stream>>>(dstp, deg, E);
        if (nb <= 1024) {
            scanA_kernel<<<nb, 256, 0, stream>>>(deg, rowptr, bsum, n);
            scanB_kernel<<<1, 1024, 0, stream>>>(bsum, nb);
            scanC_kernel<<<nb, 256, 0, stream>>>(rowptr, bsum, n);
        } else {
            scan_kernel<<<1, 1024, 0, stream>>>(deg, rowptr, n);
        }
        dis_kernel<<<(n + 255) / 256, 256, 0, stream>>>(deg, n);
        scatter_kernel<<<(E + 255) / 256, 256, 0, stream>>>(srcp, dstp, deg, rowptr, cnt, ecolw, E);

        gemm1_kernel<<<gemm_blocks, 256, 0, stream>>>(x, W1, z, n, NS);

        int sb = (4 * n + 255) / 256;
        // Horner layer 1
        spmm_csr_kernel<<<sb, 256, 0, stream>>>(z + 3 * NS, z + 2 * NS, z + 2 * NS, rowptr, ecolw, nullptr, 0, n);
        spmm_csr_kernel<<<sb, 256, 0, stream>>>(z + 2 * NS, z + 1 * NS, z + 1 * NS, rowptr, ecolw, nullptr, 0, n);
        spmm_csr_kernel<<<sb, 256, 0, stream>>>(z + 1 * NS, z,          z,          rowptr, ecolw, b1,      1, n);
        // layer 2 hops
        spmm_csr_kernel<<<sb, 256, 0, stream>>>(z,          nullptr, z + 1 * NS, rowptr, ecolw, nullptr, 0, n);
        spmm_csr_kernel<<<sb, 256, 0, stream>>>(z + 1 * NS, nullptr, z + 2 * NS, rowptr, ecolw, nullptr, 0, n);
        spmm_csr_kernel<<<sb, 256, 0, stream>>>(z + 2 * NS, nullptr, z + 3 * NS, rowptr, ecolw, nullptr, 0, n);

        gemm2_kernel<<<gemm_blocks, 256, 0, stream>>>(z, W2, bb2, out, n, NS);
    } else {
        // ---------- fallback: atomic path ----------
        float* dis2 = ws;
        size_t z2off = ((size_t)n + 3) & ~(size_t)3;
        float* z2 = ws + z2off;
        hipMemsetAsync(dis2, 0, n * sizeof(float), stream);
        deg_kernel<<<(E + 255) / 256, 256, 0, stream>>>(dstp, dis2, E);
        dis_kernel<<<(n + 255) / 256, 256, 0, stream>>>(dis2, n);
        gemm1_kernel<<<gemm_blocks, 256, 0, stream>>>(x, W1, z2, n, NS);
        int sb = (16 * E + 255) / 256;
        spmm_atomic_kernel<<<sb, 256, 0, stream>>>(z2 + 3 * NS, z2 + 2 * NS, srcp, dstp, dis2, E);
        spmm_atomic_kernel<<<sb, 256, 0, stream>>>(z2 + 2 * NS, z2 + 1 * NS, srcp, dstp, dis2, E);
        spmm_atomic_kernel<<<sb, 256, 0, stream>>>(z2 + 1 * NS, z2,          srcp, dstp, dis2, E);
        bias_relu_kernel<<<(NS + 255) / 256, 256, 0, stream>>>(z2, b1, NS);
        hipMemsetAsync(z2 + NS, 0, (size_t)3 * NS * sizeof(float), stream);
        spmm_atomic_kernel<<<sb, 256, 0, stream>>>(z2,          z2 + NS,     srcp, dstp, dis2, E);
        spmm_atomic_kernel<<<sb, 256, 0, stream>>>(z2 + NS,     z2 + 2 * NS, srcp, dstp, dis2, E);
        spmm_atomic_kernel<<<sb, 256, 0, stream>>>(z2 + 2 * NS, z2 + 3 * NS, srcp, dstp, dis2, E);
        gemm2_kernel<<<gemm_blocks, 256, 0, stream>>>(z2, W2, bb2, out, n, NS);
    }
}

// Round 8
// 263.569 us; speedup vs baseline: 1.2602x; 1.1119x over previous
//
#include <hip/hip_runtime.h>
#include <hip/hip_bf16.h>

// ---- pos pass: pos[e] = rank of edge within its dst row; cnt ends as degree ----
__global__ void pos_kernel(const int* __restrict__ dst, int* __restrict__ cnt,
                           int* __restrict__ pos, int E) {
    int e = blockIdx.x * blockDim.x + threadIdx.x;
    if (e < E) pos[e] = atomicAdd(&cnt[dst[e]], 1);
}

// ---- dis[i] = cnt>0 ? cnt^-0.5 : 0 ----
__global__ void dis_kernel(const int* __restrict__ cnt, float* __restrict__ dis, int n) {
    int i = blockIdx.x * blockDim.x + threadIdx.x;
    if (i < n) {
        int d = cnt[i];
        dis[i] = (d > 0) ? rsqrtf((float)d) : 0.0f;
    }
}

// ---- hierarchical scan pass A (int input) ----
__global__ __launch_bounds__(256) void scanA_kernel(const int* __restrict__ cnt,
                                                    int* __restrict__ rowptr,
                                                    int* __restrict__ bsum, int n) {
    __shared__ int lds[256];
    int i = blockIdx.x * 256 + threadIdx.x;
    int v = (i < n) ? cnt[i] : 0;
    lds[threadIdx.x] = v;
    __syncthreads();
    #pragma unroll
    for (int off = 1; off < 256; off <<= 1) {
        int t = (threadIdx.x >= off) ? lds[threadIdx.x - off] : 0;
        __syncthreads();
        lds[threadIdx.x] += t;
        __syncthreads();
    }
    if (i < n) rowptr[i + 1] = lds[threadIdx.x];
    if (threadIdx.x == 255) bsum[blockIdx.x] = lds[255];
}

// ---- pass B: single-block exclusive scan of block sums (nb <= 1024) ----
__global__ __launch_bounds__(1024) void scanB_kernel(int* __restrict__ bsum, int nb) {
    __shared__ int lds[1024];
    int t = threadIdx.x;
    int v = (t < nb) ? bsum[t] : 0;
    lds[t] = v;
    __syncthreads();
    #pragma unroll
    for (int off = 1; off < 1024; off <<= 1) {
        int u = (t >= off) ? lds[t - off] : 0;
        __syncthreads();
        lds[t] += u;
        __syncthreads();
    }
    if (t < nb) bsum[t] = lds[t] - v;
}

// ---- pass C: add block offsets ----
__global__ __launch_bounds__(256) void scanC_kernel(int* __restrict__ rowptr,
                                                    const int* __restrict__ bsum, int n) {
    int i = blockIdx.x * 256 + threadIdx.x;
    if (i < n) rowptr[i + 1] += bsum[blockIdx.x];
    if (i == 0) rowptr[0] = 0;
}

// ---- fallback single-block scan (n > 262144 only) ----
__global__ __launch_bounds__(1024) void scan_kernel(const int* __restrict__ cnt,
                                                    int* __restrict__ rowptr, int n) {
    __shared__ int part[1024];
    int tid = threadIdx.x;
    int chunk = (n + 1023) / 1024;
    int beg = tid * chunk;
    int end = beg + chunk; if (end > n) end = n;
    int s = 0;
    for (int i = beg; i < end; ++i) s += cnt[i];
    part[tid] = s;
    __syncthreads();
    for (int off = 1; off < 1024; off <<= 1) {
        int v = (tid >= off) ? part[tid - off] : 0;
        __syncthreads();
        part[tid] += v;
        __syncthreads();
    }
    int run = (tid > 0) ? part[tid - 1] : 0;
    if (tid == 0) rowptr[0] = 0;
    for (int i = beg; i < end; ++i) { run += cnt[i]; rowptr[i + 1] = run; }
}

// ---- atomic-free scatter: ecolw[rowptr[d]+pos[e]] = {src, dis[s]*dis[d]} ----
__global__ void scatter2_kernel(const int* __restrict__ src, const int* __restrict__ dst,
                                const int* __restrict__ pos, const float* __restrict__ dis,
                                const int* __restrict__ rowptr,
                                float2* __restrict__ ecolw, int E) {
    int e = blockIdx.x * blockDim.x + threadIdx.x;
    if (e < E) {
        int s = src[e], d = dst[e];
        ecolw[rowptr[d] + pos[e]] = make_float2(__int_as_float(s), dis[s] * dis[d]);
    }
}

// ---- GEMM1 (tiled): z_k = rownorm(x) @ W1[k]. BM=128, BN=64, K=2x64 slabs. ----
__global__ __launch_bounds__(256) void gemm1_kernel(
    const float* __restrict__ x, const float* __restrict__ W1,
    float* __restrict__ z, int n, int nstride)
{
    __shared__ float As[64 * 132];      // [kk][row]
    __shared__ float Bs[64 * 64];       // [kk][col]
    __shared__ float sums[128];
    const int t  = threadIdx.x;
    const int tx = t & 15;
    const int ty = t >> 4;
    const int c  = t & 15;
    const int g  = t >> 4;
    const int block_row = blockIdx.x * 128;

    float acc[8][4];
    #pragma unroll
    for (int i = 0; i < 8; ++i)
        #pragma unroll
        for (int j = 0; j < 4; ++j) acc[i][j] = 0.f;

    for (int kp = 0; kp < 2; ++kp) {
        #pragma unroll
        for (int i = 0; i < 8; ++i) {
            int row  = g + 16 * i;
            int grow = block_row + row;
            float v0 = 0.f, v1 = 0.f, v2 = 0.f, v3 = 0.f;
            if (grow < n) {
                const float* xp = x + (long)grow * 128 + kp * 64 + c;
                v0 = xp[0]; v1 = xp[16]; v2 = xp[32]; v3 = xp[48];
            }
            As[(c +  0) * 132 + row] = v0;
            As[(c + 16) * 132 + row] = v1;
            As[(c + 32) * 132 + row] = v2;
            As[(c + 48) * 132 + row] = v3;
            float red = (v0 + v1) + (v2 + v3);
            #pragma unroll
            for (int off = 8; off > 0; off >>= 1) red += __shfl_down(red, off, 16);
            if (c == 0) { if (kp == 0) sums[row] = red; else sums[row] += red; }
        }
        #pragma unroll
        for (int i2 = 0; i2 < 4; ++i2) {
            int kk = g + 16 * i2;
            int kglob = kp * 64 + kk;
            float4 wv = *(const float4*)(W1 + (c >> 2) * 2048 + kglob * 16 + 4 * (c & 3));
            *(float4*)(Bs + kk * 64 + 4 * c) = wv;
        }
        __syncthreads();
        #pragma unroll 4
        for (int kk = 0; kk < 64; ++kk) {
            float4 a0 = *(const float4*)(As + kk * 132 + 8 * ty);
            float4 a1 = *(const float4*)(As + kk * 132 + 8 * ty + 4);
            float4 bv = *(const float4*)(Bs + kk * 64 + 4 * tx);
            float ar[8] = {a0.x, a0.y, a0.z, a0.w, a1.x, a1.y, a1.z, a1.w};
            float br[4] = {bv.x, bv.y, bv.z, bv.w};
            #pragma unroll
            for (int i = 0; i < 8; ++i)
                #pragma unroll
                for (int j = 0; j < 4; ++j)
                    acc[i][j] += ar[i] * br[j];
        }
        __syncthreads();
    }
    int plane = tx >> 2;
    int oo4   = 4 * (tx & 3);
    #pragma unroll
    for (int i = 0; i < 8; ++i) {
        int row  = 8 * ty + i;
        int grow = block_row + row;
        if (grow < n) {
            float s = 1.0f / fmaxf(sums[row], 1e-8f);
            float4 o = make_float4(acc[i][0] * s, acc[i][1] * s, acc[i][2] * s, acc[i][3] * s);
            *(float4*)(z + (long)plane * nstride + (long)grow * 16 + oo4) = o;
        }
    }
}

// ---- GEMM2 (tiled): out = cat(G0..G3) @ W2cat + b2. BM=128, BN=64, K=64. ----
__global__ __launch_bounds__(256) void gemm2_kernel(
    const float* __restrict__ z, const float* __restrict__ W2,
    const float* __restrict__ b2, float* __restrict__ out, int n, int nstride)
{
    __shared__ float As[64 * 132];
    __shared__ float Bs[64 * 64];
    const int t  = threadIdx.x;
    const int tx = t & 15;
    const int ty = t >> 4;
    const int c  = t & 15;
    const int g  = t >> 4;
    const int block_row = blockIdx.x * 128;

    float acc[8][4];
    #pragma unroll
    for (int i = 0; i < 8; ++i)
        #pragma unroll
        for (int j = 0; j < 4; ++j) acc[i][j] = 0.f;

    #pragma unroll
    for (int i = 0; i < 8; ++i) {
        int row  = g + 16 * i;
        int grow = block_row + row;
        float v0 = 0.f, v1 = 0.f, v2 = 0.f, v3 = 0.f;
        if (grow < n) {
            const float* zp = z + (long)grow * 16 + c;
            v0 = zp[0];
            v1 = zp[(long)nstride];
            v2 = zp[2 * (long)nstride];
            v3 = zp[3 * (long)nstride];
        }
        As[(c +  0) * 132 + row] = v0;
        As[(c + 16) * 132 + row] = v1;
        As[(c + 32) * 132 + row] = v2;
        As[(c + 48) * 132 + row] = v3;
    }
    #pragma unroll
    for (int i2 = 0; i2 < 4; ++i2) {
        int j = g + 16 * i2;
        float4 wv = *(const float4*)(W2 + j * 64 + 4 * c);
        *(float4*)(Bs + j * 64 + 4 * c) = wv;
    }
    __syncthreads();
    #pragma unroll 4
    for (int kk = 0; kk < 64; ++kk) {
        float4 a0 = *(const float4*)(As + kk * 132 + 8 * ty);
        float4 a1 = *(const float4*)(As + kk * 132 + 8 * ty + 4);
        float4 bv = *(const float4*)(Bs + kk * 64 + 4 * tx);
        float ar[8] = {a0.x, a0.y, a0.z, a0.w, a1.x, a1.y, a1.z, a1.w};
        float br[4] = {bv.x, bv.y, bv.z, bv.w};
        #pragma unroll
        for (int i = 0; i < 8; ++i)
            #pragma unroll
            for (int j = 0; j < 4; ++j)
                acc[i][j] += ar[i] * br[j];
    }
    float4 bias = *(const float4*)(b2 + 4 * tx);
    #pragma unroll
    for (int i = 0; i < 8; ++i) {
        int grow = block_row + 8 * ty + i;
        if (grow < n) {
            float4 o = make_float4(acc[i][0] + bias.x, acc[i][1] + bias.y,
                                   acc[i][2] + bias.z, acc[i][3] + bias.w);
            *(float4*)(out + (long)grow * 64 + 4 * tx) = o;
        }
    }
}

// ---- CSR SpMM, float4: 4 threads/row, 4-deep unrolled gathers ----
__global__ __launch_bounds__(256) void spmm_csr_kernel(
    const float* __restrict__ in, const float* __restrict__ addsrc,
    float* __restrict__ out, const int* __restrict__ rowptr,
    const float2* __restrict__ ecolw, const float* __restrict__ b,
    int relu, int n)
{
    int t = blockIdx.x * blockDim.x + threadIdx.x;
    int r = t >> 2, q = t & 3;
    if (r >= n) return;
    int e0 = rowptr[r], e1 = rowptr[r + 1];
    float4 A0 = {0,0,0,0}, A1 = {0,0,0,0}, A2 = {0,0,0,0}, A3 = {0,0,0,0};
    int e = e0;
    for (; e + 4 <= e1; e += 4) {
        float2 c0 = ecolw[e], c1 = ecolw[e+1], c2 = ecolw[e+2], c3 = ecolw[e+3];
        float4 v0 = *((const float4*)(in + (long)__float_as_int(c0.x) * 16) + q);
        float4 v1 = *((const float4*)(in + (long)__float_as_int(c1.x) * 16) + q);
        float4 v2 = *((const float4*)(in + (long)__float_as_int(c2.x) * 16) + q);
        float4 v3 = *((const float4*)(in + (long)__float_as_int(c3.x) * 16) + q);
        A0.x += c0.y*v0.x; A0.y += c0.y*v0.y; A0.z += c0.y*v0.z; A0.w += c0.y*v0.w;
        A1.x += c1.y*v1.x; A1.y += c1.y*v1.y; A1.z += c1.y*v1.z; A1.w += c1.y*v1.w;
        A2.x += c2.y*v2.x; A2.y += c2.y*v2.y; A2.z += c2.y*v2.z; A2.w += c2.y*v2.w;
        A3.x += c3.y*v3.x; A3.y += c3.y*v3.y; A3.z += c3.y*v3.z; A3.w += c3.y*v3.w;
    }
    for (; e < e1; ++e) {
        float2 c0 = ecolw[e];
        float4 v0 = *((const float4*)(in + (long)__float_as_int(c0.x) * 16) + q);
        A0.x += c0.y*v0.x; A0.y += c0.y*v0.y; A0.z += c0.y*v0.z; A0.w += c0.y*v0.w;
    }
    float4 A = make_float4((A0.x+A1.x)+(A2.x+A3.x), (A0.y+A1.y)+(A2.y+A3.y),
                           (A0.z+A1.z)+(A2.z+A3.z), (A0.w+A1.w)+(A2.w+A3.w));
    if (addsrc) {
        float4 s = *((const float4*)(addsrc + (long)r * 16) + q);
        A.x += s.x; A.y += s.y; A.z += s.z; A.w += s.w;
    }
    if (b) {
        float4 bb = *((const float4*)b + q);
        A.x += bb.x; A.y += bb.y; A.z += bb.z; A.w += bb.w;
    }
    if (relu) {
        A.x = fmaxf(A.x, 0.f); A.y = fmaxf(A.y, 0.f);
        A.z = fmaxf(A.z, 0.f); A.w = fmaxf(A.w, 0.f);
    }
    *((float4*)(out + (long)r * 16) + q) = A;
}

// ---- fallback: edge-parallel atomic SpMM ----
__global__ __launch_bounds__(256) void spmm_atomic_kernel(
    const float* __restrict__ in, float* __restrict__ out,
    const int* __restrict__ src, const int* __restrict__ dst,
    const float* __restrict__ dis, int E)
{
    int t = blockIdx.x * blockDim.x + threadIdx.x;
    int e = t >> 4, f = t & 15;
    if (e < E) {
        int s = src[e], d = dst[e];
        atomicAdd(&out[d * 16 + f], dis[s] * dis[d] * in[s * 16 + f]);
    }
}

__global__ void deg_kernel(const int* __restrict__ dst, float* __restrict__ deg, int E) {
    int e = blockIdx.x * blockDim.x + threadIdx.x;
    if (e < E) atomicAdd(&deg[dst[e]], 1.0f);
}

__global__ void disf_kernel(float* __restrict__ deg, int n) {
    int i = blockIdx.x * blockDim.x + threadIdx.x;
    if (i < n) {
        float d = deg[i];
        deg[i] = (d > 0.0f) ? rsqrtf(d) : 0.0f;
    }
}

__global__ void bias_relu_kernel(float* __restrict__ z0, const float* __restrict__ b, int total) {
    int i = blockIdx.x * blockDim.x + threadIdx.x;
    if (i < total) {
        float v = z0[i] + b[i & 15];
        z0[i] = v > 0.0f ? v : 0.0f;
    }
}

extern "C" void kernel_launch(void* const* d_in, const int* in_sizes, int n_in,
                              void* d_out, int out_size, void* d_ws, size_t ws_size,
                              hipStream_t stream) {
    const float* x   = (const float*)d_in[0];
    const int*   ei  = (const int*)d_in[1];
    const float* W1  = (const float*)d_in[2];
    const float* b1  = (const float*)d_in[3];
    const float* W2  = (const float*)d_in[4];
    const float* bb2 = (const float*)d_in[5];
    float* out = (float*)d_out;

    const int n  = in_sizes[0] / 128;   // 50000
    const int E  = in_sizes[1] / 2;     // 800000
    const int NS = n * 16;

    const int* srcp = ei;
    const int* dstp = ei + E;

    float* ws = (float*)d_ws;
    // layout: cnt[n] | rowptr[n+1] | bsum[1024] | dis[n] | (pad) | z[4*NS] | pos[E] | ecolw[2*E]
    int*   cnt    = (int*)ws;
    int*   rowptr = (int*)(ws + n);
    int*   bsum   = (int*)(ws + 2 * n + 1);
    float* dis    = ws + 2 * n + 1 + 1024;
    size_t zoff   = ((size_t)(3 * n + 1 + 1024) + 3) & ~(size_t)3;
    float* z      = ws + zoff;
    int*   pos    = (int*)(z + 4 * (size_t)NS);
    float2* ecolw = (float2*)(z + 4 * (size_t)NS + E);
    size_t need   = (zoff + 4 * (size_t)NS + 3 * (size_t)E) * sizeof(float);

    int gemm_blocks = (n + 127) / 128;

    if (ws_size >= need) {
        // ---------- CSR path (single atomic pass) ----------
        int nb = (n + 255) / 256;
        hipMemsetAsync(cnt, 0, (size_t)n * sizeof(int), stream);
        pos_kernel<<<(E + 255) / 256, 256, 0, stream>>>(dstp, cnt, pos, E);
        if (nb <= 1024) {
            scanA_kernel<<<nb, 256, 0, stream>>>(cnt, rowptr, bsum, n);
            scanB_kernel<<<1, 1024, 0, stream>>>(bsum, nb);
            scanC_kernel<<<nb, 256, 0, stream>>>(rowptr, bsum, n);
        } else {
            scan_kernel<<<1, 1024, 0, stream>>>(cnt, rowptr, n);
        }
        dis_kernel<<<(n + 255) / 256, 256, 0, stream>>>(cnt, dis, n);
        scatter2_kernel<<<(E + 255) / 256, 256, 0, stream>>>(srcp, dstp, pos, dis, rowptr, ecolw, E);

        gemm1_kernel<<<gemm_blocks, 256, 0, stream>>>(x, W1, z, n, NS);

        int sb = (4 * n + 255) / 256;
        // Horner layer 1
        spmm_csr_kernel<<<sb, 256, 0, stream>>>(z + 3 * NS, z + 2 * NS, z + 2 * NS, rowptr, ecolw, nullptr, 0, n);
        spmm_csr_kernel<<<sb, 256, 0, stream>>>(z + 2 * NS, z + 1 * NS, z + 1 * NS, rowptr, ecolw, nullptr, 0, n);
        spmm_csr_kernel<<<sb, 256, 0, stream>>>(z + 1 * NS, z,          z,          rowptr, ecolw, b1,      1, n);
        // layer 2 hops
        spmm_csr_kernel<<<sb, 256, 0, stream>>>(z,          nullptr, z + 1 * NS, rowptr, ecolw, nullptr, 0, n);
        spmm_csr_kernel<<<sb, 256, 0, stream>>>(z + 1 * NS, nullptr, z + 2 * NS, rowptr, ecolw, nullptr, 0, n);
        spmm_csr_kernel<<<sb, 256, 0, stream>>>(z + 2 * NS, nullptr, z + 3 * NS, rowptr, ecolw, nullptr, 0, n);

        gemm2_kernel<<<gemm_blocks, 256, 0, stream>>>(z, W2, bb2, out, n, NS);
    } else {
        // ---------- fallback: atomic path ----------
        float* dis2 = ws;
        size_t z2off = ((size_t)n + 3) & ~(size_t)3;
        float* z2 = ws + z2off;
        hipMemsetAsync(dis2, 0, n * sizeof(float), stream);
        deg_kernel<<<(E + 255) / 256, 256, 0, stream>>>(dstp, dis2, E);
        disf_kernel<<<(n + 255) / 256, 256, 0, stream>>>(dis2, n);
        gemm1_kernel<<<gemm_blocks, 256, 0, stream>>>(x, W1, z2, n, NS);
        int sb = (16 * E + 255) / 256;
        spmm_atomic_kernel<<<sb, 256, 0, stream>>>(z2 + 3 * NS, z2 + 2 * NS, srcp, dstp, dis2, E);
        spmm_atomic_kernel<<<sb, 256, 0, stream>>>(z2 + 2 * NS, z2 + 1 * NS, srcp, dstp, dis2, E);
        spmm_atomic_kernel<<<sb, 256, 0, stream>>>(z2 + 1 * NS, z2,          srcp, dstp, dis2, E);
        bias_relu_kernel<<<(NS + 255) / 256, 256, 0, stream>>>(z2, b1, NS);
        hipMemsetAsync(z2 + NS, 0, (size_t)3 * NS * sizeof(float), stream);
        spmm_atomic_kernel<<<sb, 256, 0, stream>>>(z2,          z2 + NS,     srcp, dstp, dis2, E);
        spmm_atomic_kernel<<<sb, 256, 0, stream>>>(z2 + NS,     z2 + 2 * NS, srcp, dstp, dis2, E);
        spmm_atomic_kernel<<<sb, 256, 0, stream>>>(z2 + 2 * NS, z2 + 3 * NS, srcp, dstp, dis2, E);
        gemm2_kernel<<<gemm_blocks, 256, 0, stream>>>(z2, W2, bb2, out, n, NS);
    }
}

// Round 9
// 239.884 us; speedup vs baseline: 1.3846x; 1.0987x over previous
//
#include <hip/hip_runtime.h>
#include <hip/hip_bf16.h>

typedef unsigned short u16;

__device__ __forceinline__ float bf2f(u16 h) {
    return __uint_as_float(((unsigned int)h) << 16);
}
__device__ __forceinline__ u16 f2bf(float f) {
    __hip_bfloat16 h = __float2bfloat16(f);   // RNE
    return *reinterpret_cast<u16*>(&h);
}

// ---- pos pass: pos[e] = rank of edge within its dst row; cnt ends as degree ----
__global__ void pos_kernel(const int* __restrict__ dst, int* __restrict__ cnt,
                           int* __restrict__ pos, int E) {
    int e = blockIdx.x * blockDim.x + threadIdx.x;
    if (e < E) pos[e] = atomicAdd(&cnt[dst[e]], 1);
}

// ---- hierarchical scan pass A (int input) ----
__global__ __launch_bounds__(256) void scanA_kernel(const int* __restrict__ cnt,
                                                    int* __restrict__ rowptr,
                                                    int* __restrict__ bsum, int n) {
    __shared__ int lds[256];
    int i = blockIdx.x * 256 + threadIdx.x;
    int v = (i < n) ? cnt[i] : 0;
    lds[threadIdx.x] = v;
    __syncthreads();
    #pragma unroll
    for (int off = 1; off < 256; off <<= 1) {
        int t = (threadIdx.x >= off) ? lds[threadIdx.x - off] : 0;
        __syncthreads();
        lds[threadIdx.x] += t;
        __syncthreads();
    }
    if (i < n) rowptr[i + 1] = lds[threadIdx.x];
    if (threadIdx.x == 255) bsum[blockIdx.x] = lds[255];
}

// ---- pass B: single-block exclusive scan of block sums (nb <= 1024) ----
__global__ __launch_bounds__(1024) void scanB_kernel(int* __restrict__ bsum, int nb) {
    __shared__ int lds[1024];
    int t = threadIdx.x;
    int v = (t < nb) ? bsum[t] : 0;
    lds[t] = v;
    __syncthreads();
    #pragma unroll
    for (int off = 1; off < 1024; off <<= 1) {
        int u = (t >= off) ? lds[t - off] : 0;
        __syncthreads();
        lds[t] += u;
        __syncthreads();
    }
    if (t < nb) bsum[t] = lds[t] - v;
}

// ---- pass C + dis fused ----
__global__ __launch_bounds__(256) void scanC_dis_kernel(int* __restrict__ rowptr,
                                                        const int* __restrict__ bsum,
                                                        const int* __restrict__ cnt,
                                                        float* __restrict__ dis, int n) {
    int i = blockIdx.x * 256 + threadIdx.x;
    if (i < n) {
        rowptr[i + 1] += bsum[blockIdx.x];
        int d = cnt[i];
        dis[i] = (d > 0) ? rsqrtf((float)d) : 0.0f;
    }
    if (i == 0) rowptr[0] = 0;
}

// ---- fallback single-block scan (n > 262144 only) ----
__global__ __launch_bounds__(1024) void scan_kernel(const int* __restrict__ cnt,
                                                    int* __restrict__ rowptr, int n) {
    __shared__ int part[1024];
    int tid = threadIdx.x;
    int chunk = (n + 1023) / 1024;
    int beg = tid * chunk;
    int end = beg + chunk; if (end > n) end = n;
    int s = 0;
    for (int i = beg; i < end; ++i) s += cnt[i];
    part[tid] = s;
    __syncthreads();
    for (int off = 1; off < 1024; off <<= 1) {
        int v = (tid >= off) ? part[tid - off] : 0;
        __syncthreads();
        part[tid] += v;
        __syncthreads();
    }
    int run = (tid > 0) ? part[tid - 1] : 0;
    if (tid == 0) rowptr[0] = 0;
    for (int i = beg; i < end; ++i) { run += cnt[i]; rowptr[i + 1] = run; }
}

__global__ void dis_only_kernel(const int* __restrict__ cnt, float* __restrict__ dis, int n) {
    int i = blockIdx.x * blockDim.x + threadIdx.x;
    if (i < n) {
        int d = cnt[i];
        dis[i] = (d > 0) ? rsqrtf((float)d) : 0.0f;
    }
}

// ---- atomic-free scatter: ecolw[rowptr[d]+pos[e]] = {src, dis[s]*dis[d]} ----
__global__ void scatter2_kernel(const int* __restrict__ src, const int* __restrict__ dst,
                                const int* __restrict__ pos, const float* __restrict__ dis,
                                const int* __restrict__ rowptr,
                                float2* __restrict__ ecolw, int E) {
    int e = blockIdx.x * blockDim.x + threadIdx.x;
    if (e < E) {
        int s = src[e], d = dst[e];
        ecolw[rowptr[d] + pos[e]] = make_float2(__int_as_float(s), dis[s] * dis[d]);
    }
}

// ---- GEMM1 (tiled, bf16 planes out): z_k = rownorm(x) @ W1[k] ----
__global__ __launch_bounds__(256) void gemm1_bf_kernel(
    const float* __restrict__ x, const float* __restrict__ W1,
    u16* __restrict__ zb, int n, int nstride)
{
    __shared__ float As[64 * 132];
    __shared__ float Bs[64 * 64];
    __shared__ float sums[128];
    const int t  = threadIdx.x;
    const int tx = t & 15;
    const int ty = t >> 4;
    const int c  = t & 15;
    const int g  = t >> 4;
    const int block_row = blockIdx.x * 128;

    float acc[8][4];
    #pragma unroll
    for (int i = 0; i < 8; ++i)
        #pragma unroll
        for (int j = 0; j < 4; ++j) acc[i][j] = 0.f;

    for (int kp = 0; kp < 2; ++kp) {
        #pragma unroll
        for (int i = 0; i < 8; ++i) {
            int row  = g + 16 * i;
            int grow = block_row + row;
            float v0 = 0.f, v1 = 0.f, v2 = 0.f, v3 = 0.f;
            if (grow < n) {
                const float* xp = x + (long)grow * 128 + kp * 64 + c;
                v0 = xp[0]; v1 = xp[16]; v2 = xp[32]; v3 = xp[48];
            }
            As[(c +  0) * 132 + row] = v0;
            As[(c + 16) * 132 + row] = v1;
            As[(c + 32) * 132 + row] = v2;
            As[(c + 48) * 132 + row] = v3;
            float red = (v0 + v1) + (v2 + v3);
            #pragma unroll
            for (int off = 8; off > 0; off >>= 1) red += __shfl_down(red, off, 16);
            if (c == 0) { if (kp == 0) sums[row] = red; else sums[row] += red; }
        }
        #pragma unroll
        for (int i2 = 0; i2 < 4; ++i2) {
            int kk = g + 16 * i2;
            int kglob = kp * 64 + kk;
            float4 wv = *(const float4*)(W1 + (c >> 2) * 2048 + kglob * 16 + 4 * (c & 3));
            *(float4*)(Bs + kk * 64 + 4 * c) = wv;
        }
        __syncthreads();
        #pragma unroll 4
        for (int kk = 0; kk < 64; ++kk) {
            float4 a0 = *(const float4*)(As + kk * 132 + 8 * ty);
            float4 a1 = *(const float4*)(As + kk * 132 + 8 * ty + 4);
            float4 bv = *(const float4*)(Bs + kk * 64 + 4 * tx);
            float ar[8] = {a0.x, a0.y, a0.z, a0.w, a1.x, a1.y, a1.z, a1.w};
            float br[4] = {bv.x, bv.y, bv.z, bv.w};
            #pragma unroll
            for (int i = 0; i < 8; ++i)
                #pragma unroll
                for (int j = 0; j < 4; ++j)
                    acc[i][j] += ar[i] * br[j];
        }
        __syncthreads();
    }
    int plane = tx >> 2;
    int oo4   = 4 * (tx & 3);
    #pragma unroll
    for (int i = 0; i < 8; ++i) {
        int row  = 8 * ty + i;
        int grow = block_row + row;
        if (grow < n) {
            float s = 1.0f / fmaxf(sums[row], 1e-8f);
            ushort4 o;
            o.x = f2bf(acc[i][0] * s); o.y = f2bf(acc[i][1] * s);
            o.z = f2bf(acc[i][2] * s); o.w = f2bf(acc[i][3] * s);
            *(ushort4*)(zb + (long)plane * nstride + (long)grow * 16 + oo4) = o;
        }
    }
}

// ---- CSR SpMM on bf16 planes: 4 lanes/row, 8B gathers, fp32 accumulate ----
__global__ __launch_bounds__(256) void spmm_csr_bf_kernel(
    const u16* __restrict__ in, const u16* __restrict__ addsrc,
    u16* __restrict__ out, const int* __restrict__ rowptr,
    const float2* __restrict__ ecolw, const float* __restrict__ b,
    int relu, int n)
{
    int t = blockIdx.x * blockDim.x + threadIdx.x;
    int r = t >> 2, q = t & 3;
    if (r >= n) return;
    int e0 = rowptr[r], e1 = rowptr[r + 1];
    float a0x=0,a0y=0,a0z=0,a0w=0, a1x=0,a1y=0,a1z=0,a1w=0;
    float a2x=0,a2y=0,a2z=0,a2w=0, a3x=0,a3y=0,a3z=0,a3w=0;
    int e = e0;
    for (; e + 4 <= e1; e += 4) {
        float2 c0 = ecolw[e], c1 = ecolw[e+1], c2 = ecolw[e+2], c3 = ecolw[e+3];
        ushort4 v0 = *((const ushort4*)(in + (long)__float_as_int(c0.x) * 16) + q);
        ushort4 v1 = *((const ushort4*)(in + (long)__float_as_int(c1.x) * 16) + q);
        ushort4 v2 = *((const ushort4*)(in + (long)__float_as_int(c2.x) * 16) + q);
        ushort4 v3 = *((const ushort4*)(in + (long)__float_as_int(c3.x) * 16) + q);
        a0x += c0.y * bf2f(v0.x); a0y += c0.y * bf2f(v0.y); a0z += c0.y * bf2f(v0.z); a0w += c0.y * bf2f(v0.w);
        a1x += c1.y * bf2f(v1.x); a1y += c1.y * bf2f(v1.y); a1z += c1.y * bf2f(v1.z); a1w += c1.y * bf2f(v1.w);
        a2x += c2.y * bf2f(v2.x); a2y += c2.y * bf2f(v2.y); a2z += c2.y * bf2f(v2.z); a2w += c2.y * bf2f(v2.w);
        a3x += c3.y * bf2f(v3.x); a3y += c3.y * bf2f(v3.y); a3z += c3.y * bf2f(v3.z); a3w += c3.y * bf2f(v3.w);
    }
    for (; e < e1; ++e) {
        float2 c0 = ecolw[e];
        ushort4 v0 = *((const ushort4*)(in + (long)__float_as_int(c0.x) * 16) + q);
        a0x += c0.y * bf2f(v0.x); a0y += c0.y * bf2f(v0.y); a0z += c0.y * bf2f(v0.z); a0w += c0.y * bf2f(v0.w);
    }
    float Ax = (a0x+a1x)+(a2x+a3x), Ay = (a0y+a1y)+(a2y+a3y);
    float Az = (a0z+a1z)+(a2z+a3z), Aw = (a0w+a1w)+(a2w+a3w);
    if (addsrc) {
        ushort4 s = *((const ushort4*)(addsrc + (long)r * 16) + q);
        Ax += bf2f(s.x); Ay += bf2f(s.y); Az += bf2f(s.z); Aw += bf2f(s.w);
    }
    if (b) {
        float4 bb = *((const float4*)b + q);
        Ax += bb.x; Ay += bb.y; Az += bb.z; Aw += bb.w;
    }
    if (relu) {
        Ax = fmaxf(Ax, 0.f); Ay = fmaxf(Ay, 0.f);
        Az = fmaxf(Az, 0.f); Aw = fmaxf(Aw, 0.f);
    }
    ushort4 o; o.x = f2bf(Ax); o.y = f2bf(Ay); o.z = f2bf(Az); o.w = f2bf(Aw);
    *((ushort4*)(out + (long)r * 16) + q) = o;
}

// ---- GEMM2 (tiled, bf16 planes in, fp32 out): out = cat(G0..G3) @ W2cat + b2 ----
__global__ __launch_bounds__(256) void gemm2_bf_kernel(
    const u16* __restrict__ zb, const float* __restrict__ W2,
    const float* __restrict__ b2, float* __restrict__ out, int n, int nstride)
{
    __shared__ float As[64 * 132];
    __shared__ float Bs[64 * 64];
    const int t  = threadIdx.x;
    const int tx = t & 15;
    const int ty = t >> 4;
    const int c  = t & 15;
    const int g  = t >> 4;
    const int block_row = blockIdx.x * 128;

    float acc[8][4];
    #pragma unroll
    for (int i = 0; i < 8; ++i)
        #pragma unroll
        for (int j = 0; j < 4; ++j) acc[i][j] = 0.f;

    #pragma unroll
    for (int i = 0; i < 8; ++i) {
        int row  = g + 16 * i;
        int grow = block_row + row;
        float v0 = 0.f, v1 = 0.f, v2 = 0.f, v3 = 0.f;
        if (grow < n) {
            const u16* zp = zb + (long)grow * 16 + c;
            v0 = bf2f(zp[0]);
            v1 = bf2f(zp[(long)nstride]);
            v2 = bf2f(zp[2 * (long)nstride]);
            v3 = bf2f(zp[3 * (long)nstride]);
        }
        As[(c +  0) * 132 + row] = v0;
        As[(c + 16) * 132 + row] = v1;
        As[(c + 32) * 132 + row] = v2;
        As[(c + 48) * 132 + row] = v3;
    }
    #pragma unroll
    for (int i2 = 0; i2 < 4; ++i2) {
        int j = g + 16 * i2;
        float4 wv = *(const float4*)(W2 + j * 64 + 4 * c);
        *(float4*)(Bs + j * 64 + 4 * c) = wv;
    }
    __syncthreads();
    #pragma unroll 4
    for (int kk = 0; kk < 64; ++kk) {
        float4 a0 = *(const float4*)(As + kk * 132 + 8 * ty);
        float4 a1 = *(const float4*)(As + kk * 132 + 8 * ty + 4);
        float4 bv = *(const float4*)(Bs + kk * 64 + 4 * tx);
        float ar[8] = {a0.x, a0.y, a0.z, a0.w, a1.x, a1.y, a1.z, a1.w};
        float br[4] = {bv.x, bv.y, bv.z, bv.w};
        #pragma unroll
        for (int i = 0; i < 8; ++i)
            #pragma unroll
            for (int j = 0; j < 4; ++j)
                acc[i][j] += ar[i] * br[j];
    }
    float4 bias = *(const float4*)(b2 + 4 * tx);
    #pragma unroll
    for (int i = 0; i < 8; ++i) {
        int grow = block_row + 8 * ty + i;
        if (grow < n) {
            float4 o = make_float4(acc[i][0] + bias.x, acc[i][1] + bias.y,
                                   acc[i][2] + bias.z, acc[i][3] + bias.w);
            *(float4*)(out + (long)grow * 64 + 4 * tx) = o;
        }
    }
}

// ================= fp32 fallback path (small workspace) =================
__global__ void deg_kernel(const int* __restrict__ dst, float* __restrict__ deg, int E) {
    int e = blockIdx.x * blockDim.x + threadIdx.x;
    if (e < E) atomicAdd(&deg[dst[e]], 1.0f);
}
__global__ void disf_kernel(float* __restrict__ deg, int n) {
    int i = blockIdx.x * blockDim.x + threadIdx.x;
    if (i < n) {
        float d = deg[i];
        deg[i] = (d > 0.0f) ? rsqrtf(d) : 0.0f;
    }
}
__global__ __launch_bounds__(256) void gemm1_f32_kernel(
    const float* __restrict__ x, const float* __restrict__ W1,
    float* __restrict__ z, int n, int nstride)
{
    __shared__ float As[64 * 132];
    __shared__ float Bs[64 * 64];
    __shared__ float sums[128];
    const int t  = threadIdx.x;
    const int tx = t & 15;
    const int ty = t >> 4;
    const int c  = t & 15;
    const int g  = t >> 4;
    const int block_row = blockIdx.x * 128;
    float acc[8][4];
    #pragma unroll
    for (int i = 0; i < 8; ++i)
        #pragma unroll
        for (int j = 0; j < 4; ++j) acc[i][j] = 0.f;
    for (int kp = 0; kp < 2; ++kp) {
        #pragma unroll
        for (int i = 0; i < 8; ++i) {
            int row  = g + 16 * i;
            int grow = block_row + row;
            float v0 = 0.f, v1 = 0.f, v2 = 0.f, v3 = 0.f;
            if (grow < n) {
                const float* xp = x + (long)grow * 128 + kp * 64 + c;
                v0 = xp[0]; v1 = xp[16]; v2 = xp[32]; v3 = xp[48];
            }
            As[(c +  0) * 132 + row] = v0;
            As[(c + 16) * 132 + row] = v1;
            As[(c + 32) * 132 + row] = v2;
            As[(c + 48) * 132 + row] = v3;
            float red = (v0 + v1) + (v2 + v3);
            #pragma unroll
            for (int off = 8; off > 0; off >>= 1) red += __shfl_down(red, off, 16);
            if (c == 0) { if (kp == 0) sums[row] = red; else sums[row] += red; }
        }
        #pragma unroll
        for (int i2 = 0; i2 < 4; ++i2) {
            int kk = g + 16 * i2;
            int kglob = kp * 64 + kk;
            float4 wv = *(const float4*)(W1 + (c >> 2) * 2048 + kglob * 16 + 4 * (c & 3));
            *(float4*)(Bs + kk * 64 + 4 * c) = wv;
        }
        __syncthreads();
        #pragma unroll 4
        for (int kk = 0; kk < 64; ++kk) {
            float4 a0 = *(const float4*)(As + kk * 132 + 8 * ty);
            float4 a1 = *(const float4*)(As + kk * 132 + 8 * ty + 4);
            float4 bv = *(const float4*)(Bs + kk * 64 + 4 * tx);
            float ar[8] = {a0.x, a0.y, a0.z, a0.w, a1.x, a1.y, a1.z, a1.w};
            float br[4] = {bv.x, bv.y, bv.z, bv.w};
            #pragma unroll
            for (int i = 0; i < 8; ++i)
                #pragma unroll
                for (int j = 0; j < 4; ++j)
                    acc[i][j] += ar[i] * br[j];
        }
        __syncthreads();
    }
    int plane = tx >> 2;
    int oo4   = 4 * (tx & 3);
    #pragma unroll
    for (int i = 0; i < 8; ++i) {
        int row  = 8 * ty + i;
        int grow = block_row + row;
        if (grow < n) {
            float s = 1.0f / fmaxf(sums[row], 1e-8f);
            float4 o = make_float4(acc[i][0] * s, acc[i][1] * s, acc[i][2] * s, acc[i][3] * s);
            *(float4*)(z + (long)plane * nstride + (long)grow * 16 + oo4) = o;
        }
    }
}
__global__ __launch_bounds__(256) void spmm_atomic_kernel(
    const float* __restrict__ in, float* __restrict__ out,
    const int* __restrict__ src, const int* __restrict__ dst,
    const float* __restrict__ dis, int E)
{
    int t = blockIdx.x * blockDim.x + threadIdx.x;
    int e = t >> 4, f = t & 15;
    if (e < E) {
        int s = src[e], d = dst[e];
        atomicAdd(&out[d * 16 + f], dis[s] * dis[d] * in[s * 16 + f]);
    }
}
__global__ void bias_relu_kernel(float* __restrict__ z0, const float* __restrict__ b, int total) {
    int i = blockIdx.x * blockDim.x + threadIdx.x;
    if (i < total) {
        float v = z0[i] + b[i & 15];
        z0[i] = v > 0.0f ? v : 0.0f;
    }
}
__global__ __launch_bounds__(256) void gemm2_f32_kernel(
    const float* __restrict__ z, const float* __restrict__ W2,
    const float* __restrict__ b2, float* __restrict__ out, int n, int nstride)
{
    __shared__ float As[64 * 132];
    __shared__ float Bs[64 * 64];
    const int t  = threadIdx.x;
    const int tx = t & 15;
    const int ty = t >> 4;
    const int c  = t & 15;
    const int g  = t >> 4;
    const int block_row = blockIdx.x * 128;
    float acc[8][4];
    #pragma unroll
    for (int i = 0; i < 8; ++i)
        #pragma unroll
        for (int j = 0; j < 4; ++j) acc[i][j] = 0.f;
    #pragma unroll
    for (int i = 0; i < 8; ++i) {
        int row  = g + 16 * i;
        int grow = block_row + row;
        float v0 = 0.f, v1 = 0.f, v2 = 0.f, v3 = 0.f;
        if (grow < n) {
            const float* zp = z + (long)grow * 16 + c;
            v0 = zp[0];
            v1 = zp[(long)nstride];
            v2 = zp[2 * (long)nstride];
            v3 = zp[3 * (long)nstride];
        }
        As[(c +  0) * 132 + row] = v0;
        As[(c + 16) * 132 + row] = v1;
        As[(c + 32) * 132 + row] = v2;
        As[(c + 48) * 132 + row] = v3;
    }
    #pragma unroll
    for (int i2 = 0; i2 < 4; ++i2) {
        int j = g + 16 * i2;
        float4 wv = *(const float4*)(W2 + j * 64 + 4 * c);
        *(float4*)(Bs + j * 64 + 4 * c) = wv;
    }
    __syncthreads();
    #pragma unroll 4
    for (int kk = 0; kk < 64; ++kk) {
        float4 a0 = *(const float4*)(As + kk * 132 + 8 * ty);
        float4 a1 = *(const float4*)(As + kk * 132 + 8 * ty + 4);
        float4 bv = *(const float4*)(Bs + kk * 64 + 4 * tx);
        float ar[8] = {a0.x, a0.y, a0.z, a0.w, a1.x, a1.y, a1.z, a1.w};
        float br[4] = {bv.x, bv.y, bv.z, bv.w};
        #pragma unroll
        for (int i = 0; i < 8; ++i)
            #pragma unroll
            for (int j = 0; j < 4; ++j)
                acc[i][j] += ar[i] * br[j];
    }
    float4 bias = *(const float4*)(b2 + 4 * tx);
    #pragma unroll
    for (int i = 0; i < 8; ++i) {
        int grow = block_row + 8 * ty + i;
        if (grow < n) {
            float4 o = make_float4(acc[i][0] + bias.x, acc[i][1] + bias.y,
                                   acc[i][2] + bias.z, acc[i][3] + bias.w);
            *(float4*)(out + (long)grow * 64 + 4 * tx) = o;
        }
    }
}

static inline size_t align16(size_t v) { return (v + 15) & ~(size_t)15; }

extern "C" void kernel_launch(void* const* d_in, const int* in_sizes, int n_in,
                              void* d_out, int out_size, void* d_ws, size_t ws_size,
                              hipStream_t stream) {
    const float* x   = (const float*)d_in[0];
    const int*   ei  = (const int*)d_in[1];
    const float* W1  = (const float*)d_in[2];
    const float* b1  = (const float*)d_in[3];
    const float* W2  = (const float*)d_in[4];
    const float* bb2 = (const float*)d_in[5];
    float* out = (float*)d_out;

    const int n  = in_sizes[0] / 128;   // 50000
    const int E  = in_sizes[1] / 2;     // 800000
    const int NS = n * 16;

    const int* srcp = ei;
    const int* dstp = ei + E;

    char* wsb = (char*)d_ws;
    // bytes layout: cnt[n] | rowptr[n+1] | bsum[1024] | dis[n] | zb[4*NS bf16] | pos[E] | ecolw[E f2]
    int*   cnt    = (int*)wsb;
    int*   rowptr = (int*)(wsb + (size_t)4 * n);
    int*   bsum   = (int*)(wsb + (size_t)4 * (2 * n + 1));
    float* dis    = (float*)(wsb + (size_t)4 * (2 * n + 1 + 1024));
    size_t zoffb  = align16((size_t)4 * (3 * n + 1 + 1024));
    u16*   zb     = (u16*)(wsb + zoffb);
    size_t posoff = align16(zoffb + (size_t)2 * 4 * NS);
    int*   pos    = (int*)(wsb + posoff);
    size_t ecooff = align16(posoff + (size_t)4 * E);
    float2* ecolw = (float2*)(wsb + ecooff);
    size_t need   = ecooff + (size_t)8 * E;

    int gemm_blocks = (n + 127) / 128;

    if (ws_size >= need) {
        // ---------- CSR + bf16-plane path ----------
        int nb = (n + 255) / 256;
        hipMemsetAsync(cnt, 0, (size_t)n * sizeof(int), stream);
        pos_kernel<<<(E + 255) / 256, 256, 0, stream>>>(dstp, cnt, pos, E);
        if (nb <= 1024) {
            scanA_kernel<<<nb, 256, 0, stream>>>(cnt, rowptr, bsum, n);
            scanB_kernel<<<1, 1024, 0, stream>>>(bsum, nb);
            scanC_dis_kernel<<<nb, 256, 0, stream>>>(rowptr, bsum, cnt, dis, n);
        } else {
            scan_kernel<<<1, 1024, 0, stream>>>(cnt, rowptr, n);
            dis_only_kernel<<<(n + 255) / 256, 256, 0, stream>>>(cnt, dis, n);
        }
        scatter2_kernel<<<(E + 255) / 256, 256, 0, stream>>>(srcp, dstp, pos, dis, rowptr, ecolw, E);

        gemm1_bf_kernel<<<gemm_blocks, 256, 0, stream>>>(x, W1, zb, n, NS);

        int sb = (4 * n + 255) / 256;
        // layer-1 Horner
        spmm_csr_bf_kernel<<<sb, 256, 0, stream>>>(zb + 3 * NS, zb + 2 * NS, zb + 2 * NS, rowptr, ecolw, nullptr, 0, n);
        spmm_csr_bf_kernel<<<sb, 256, 0, stream>>>(zb + 2 * NS, zb + 1 * NS, zb + 1 * NS, rowptr, ecolw, nullptr, 0, n);
        spmm_csr_bf_kernel<<<sb, 256, 0, stream>>>(zb + 1 * NS, zb,          zb,          rowptr, ecolw, b1,      1, n);
        // layer-2 hops
        spmm_csr_bf_kernel<<<sb, 256, 0, stream>>>(zb,          nullptr, zb + 1 * NS, rowptr, ecolw, nullptr, 0, n);
        spmm_csr_bf_kernel<<<sb, 256, 0, stream>>>(zb + 1 * NS, nullptr, zb + 2 * NS, rowptr, ecolw, nullptr, 0, n);
        spmm_csr_bf_kernel<<<sb, 256, 0, stream>>>(zb + 2 * NS, nullptr, zb + 3 * NS, rowptr, ecolw, nullptr, 0, n);

        gemm2_bf_kernel<<<gemm_blocks, 256, 0, stream>>>(zb, W2, bb2, out, n, NS);
    } else {
        // ---------- fp32 atomic fallback ----------
        float* ws = (float*)d_ws;
        float* dis2 = ws;
        size_t z2off = ((size_t)n + 3) & ~(size_t)3;
        float* z2 = ws + z2off;
        hipMemsetAsync(dis2, 0, n * sizeof(float), stream);
        deg_kernel<<<(E + 255) / 256, 256, 0, stream>>>(dstp, dis2, E);
        disf_kernel<<<(n + 255) / 256, 256, 0, stream>>>(dis2, n);
        gemm1_f32_kernel<<<gemm_blocks, 256, 0, stream>>>(x, W1, z2, n, NS);
        int sb = (16 * E + 255) / 256;
        spmm_atomic_kernel<<<sb, 256, 0, stream>>>(z2 + 3 * NS, z2 + 2 * NS, srcp, dstp, dis2, E);
        spmm_atomic_kernel<<<sb, 256, 0, stream>>>(z2 + 2 * NS, z2 + 1 * NS, srcp, dstp, dis2, E);
        spmm_atomic_kernel<<<sb, 256, 0, stream>>>(z2 + 1 * NS, z2,          srcp, dstp, dis2, E);
        bias_relu_kernel<<<(NS + 255) / 256, 256, 0, stream>>>(z2, b1, NS);
        hipMemsetAsync(z2 + NS, 0, (size_t)3 * NS * sizeof(float), stream);
        spmm_atomic_kernel<<<sb, 256, 0, stream>>>(z2,          z2 + NS,     srcp, dstp, dis2, E);
        spmm_atomic_kernel<<<sb, 256, 0, stream>>>(z2 + NS,     z2 + 2 * NS, srcp, dstp, dis2, E);
        spmm_atomic_kernel<<<sb, 256, 0, stream>>>(z2 + 2 * NS, z2 + 3 * NS, srcp, dstp, dis2, E);
        gemm2_f32_kernel<<<gemm_blocks, 256, 0, stream>>>(z2, W2, bb2, out, n, NS);
    }
}

// Round 10
// 214.672 us; speedup vs baseline: 1.5473x; 1.1174x over previous
//
#include <hip/hip_runtime.h>
#include <hip/hip_bf16.h>

typedef unsigned short u16;

__device__ __forceinline__ float bf2f(u16 h) {
    return __uint_as_float(((unsigned int)h) << 16);
}
__device__ __forceinline__ u16 f2bf(float f) {
    __hip_bfloat16 h = __float2bfloat16(f);   // RNE
    return *reinterpret_cast<u16*>(&h);
}

#define BKT_SHIFT 7
#define BKT_SIZE  128
#define CHUNK     2048   // edges per hist/scatter block (256 thr x 8)

// ---- A1: per-chunk LDS histogram over buckets (dst>>7). No global atomics. ----
__global__ __launch_bounds__(256) void hist_kernel(const int* __restrict__ dst,
                                                   int* __restrict__ hist,
                                                   int E, int nbA, int nbuck) {
    __shared__ int lh[512];
    for (int j = threadIdx.x; j < nbuck; j += 256) lh[j] = 0;
    __syncthreads();
    int base = blockIdx.x * CHUNK;
    int end  = min(E, base + CHUNK);
    for (int e = base + threadIdx.x; e < end; e += 256)
        atomicAdd(&lh[dst[e] >> BKT_SHIFT], 1);
    __syncthreads();
    for (int j = threadIdx.x; j < nbuck; j += 256)
        hist[j * nbA + blockIdx.x] = lh[j];       // bin-major for the scan
}

// ---- hierarchical scan (generic, int) ----
__global__ __launch_bounds__(256) void scanA_kernel(const int* __restrict__ in,
                                                    int* __restrict__ outp1,
                                                    int* __restrict__ bsum, int n) {
    __shared__ int lds[256];
    int i = blockIdx.x * 256 + threadIdx.x;
    int v = (i < n) ? in[i] : 0;
    lds[threadIdx.x] = v;
    __syncthreads();
    #pragma unroll
    for (int off = 1; off < 256; off <<= 1) {
        int t = (threadIdx.x >= off) ? lds[threadIdx.x - off] : 0;
        __syncthreads();
        lds[threadIdx.x] += t;
        __syncthreads();
    }
    if (i < n) outp1[i + 1] = lds[threadIdx.x];
    if (threadIdx.x == 255) bsum[blockIdx.x] = lds[255];
}
__global__ __launch_bounds__(1024) void scanB_kernel(int* __restrict__ bsum, int nb) {
    __shared__ int lds[1024];
    int t = threadIdx.x;
    int v = (t < nb) ? bsum[t] : 0;
    lds[t] = v;
    __syncthreads();
    #pragma unroll
    for (int off = 1; off < 1024; off <<= 1) {
        int u = (t >= off) ? lds[t - off] : 0;
        __syncthreads();
        lds[t] += u;
        __syncthreads();
    }
    if (t < nb) bsum[t] = lds[t] - v;
}
__global__ __launch_bounds__(256) void scanC_kernel(int* __restrict__ outp1,
                                                    const int* __restrict__ bsum, int n) {
    int i = blockIdx.x * 256 + threadIdx.x;
    if (i < n) outp1[i + 1] += bsum[blockIdx.x];
    if (i == 0) outp1[0] = 0;
}

// ---- A3: scatter edges into bucket-grouped array (LDS-atomic local ranks) ----
__global__ __launch_bounds__(256) void bucket_scatter_kernel(
    const int* __restrict__ src, const int* __restrict__ dst,
    const int* __restrict__ hofs, int2* __restrict__ bucketed,
    int E, int nbA, int nbuck)
{
    __shared__ int lbase[512];
    __shared__ int lcnt[512];
    for (int j = threadIdx.x; j < nbuck; j += 256) {
        lbase[j] = hofs[j * nbA + blockIdx.x];
        lcnt[j] = 0;
    }
    __syncthreads();
    int base = blockIdx.x * CHUNK;
    int end  = min(E, base + CHUNK);
    for (int e = base + threadIdx.x; e < end; e += 256) {
        int d = dst[e];
        int b = d >> BKT_SHIFT;
        int r = atomicAdd(&lcnt[b], 1);
        bucketed[lbase[b] + r] = make_int2(src[e], d);
    }
}

// ---- B: one block per bucket -> rowptr, dis, ecolw (weight = dis_dst staged) ----
__global__ __launch_bounds__(256) void csr_finalize_kernel(
    const int2* __restrict__ bucketed, const int* __restrict__ hofs,
    int* __restrict__ rowptr, float* __restrict__ dis,
    float2* __restrict__ ecolw, int E, int nbA, int nbuck, int n)
{
    __shared__ int cnt[BKT_SIZE];
    __shared__ int run[BKT_SIZE];
    __shared__ float disl[BKT_SIZE];
    int b = blockIdx.x;
    int bstart = hofs[b * nbA];
    int bend   = (b == nbuck - 1) ? E : hofs[(b + 1) * nbA];
    for (int j = threadIdx.x; j < BKT_SIZE; j += 256) cnt[j] = 0;
    __syncthreads();
    for (int i = bstart + threadIdx.x; i < bend; i += 256)
        atomicAdd(&cnt[bucketed[i].y & (BKT_SIZE - 1)], 1);
    __syncthreads();
    if (threadIdx.x == 0) {
        int runacc = 0;
        for (int j = 0; j < BKT_SIZE; ++j) {
            int c = cnt[j];
            run[j] = runacc;          // exclusive prefix (local)
            runacc += c;
        }
    }
    __syncthreads();
    // write rowptr/dis for this bucket's dsts
    for (int j = threadIdx.x; j < BKT_SIZE; j += 256) {
        int d = b * BKT_SIZE + j;
        if (d < n) {
            rowptr[d] = bstart + run[j];
            int c = cnt[j];
            float dv = (c > 0) ? rsqrtf((float)c) : 0.0f;
            dis[d] = dv;
            disl[j] = dv;
        }
    }
    if (b == 0 && threadIdx.x == 0) rowptr[n] = E;
    __syncthreads();
    for (int i = bstart + threadIdx.x; i < bend; i += 256) {
        int2 p = bucketed[i];
        int j = p.y & (BKT_SIZE - 1);
        int r = atomicAdd(&run[j], 1);
        ecolw[bstart + r] = make_float2(__int_as_float(p.x), disl[j]);
    }
}

// ---- W: ecolw[e].y = staged dis_dst * dis[src] (the one random gather pass) ----
__global__ __launch_bounds__(256) void weight_kernel(float2* __restrict__ ecolw,
                                                     const float* __restrict__ dis, int E) {
    int e = blockIdx.x * blockDim.x + threadIdx.x;
    if (e < E) {
        float2 c = ecolw[e];
        ecolw[e].y = c.y * dis[__float_as_int(c.x)];
    }
}

// ---- GEMM1 (tiled, bf16 planes out): z_k = rownorm(x) @ W1[k] ----
__global__ __launch_bounds__(256) void gemm1_bf_kernel(
    const float* __restrict__ x, const float* __restrict__ W1,
    u16* __restrict__ zb, int n, int nstride)
{
    __shared__ float As[64 * 132];
    __shared__ float Bs[64 * 64];
    __shared__ float sums[128];
    const int t  = threadIdx.x;
    const int tx = t & 15;
    const int ty = t >> 4;
    const int c  = t & 15;
    const int g  = t >> 4;
    const int block_row = blockIdx.x * 128;

    float acc[8][4];
    #pragma unroll
    for (int i = 0; i < 8; ++i)
        #pragma unroll
        for (int j = 0; j < 4; ++j) acc[i][j] = 0.f;

    for (int kp = 0; kp < 2; ++kp) {
        #pragma unroll
        for (int i = 0; i < 8; ++i) {
            int row  = g + 16 * i;
            int grow = block_row + row;
            float v0 = 0.f, v1 = 0.f, v2 = 0.f, v3 = 0.f;
            if (grow < n) {
                const float* xp = x + (long)grow * 128 + kp * 64 + c;
                v0 = xp[0]; v1 = xp[16]; v2 = xp[32]; v3 = xp[48];
            }
            As[(c +  0) * 132 + row] = v0;
            As[(c + 16) * 132 + row] = v1;
            As[(c + 32) * 132 + row] = v2;
            As[(c + 48) * 132 + row] = v3;
            float red = (v0 + v1) + (v2 + v3);
            #pragma unroll
            for (int off = 8; off > 0; off >>= 1) red += __shfl_down(red, off, 16);
            if (c == 0) { if (kp == 0) sums[row] = red; else sums[row] += red; }
        }
        #pragma unroll
        for (int i2 = 0; i2 < 4; ++i2) {
            int kk = g + 16 * i2;
            int kglob = kp * 64 + kk;
            float4 wv = *(const float4*)(W1 + (c >> 2) * 2048 + kglob * 16 + 4 * (c & 3));
            *(float4*)(Bs + kk * 64 + 4 * c) = wv;
        }
        __syncthreads();
        #pragma unroll 4
        for (int kk = 0; kk < 64; ++kk) {
            float4 a0 = *(const float4*)(As + kk * 132 + 8 * ty);
            float4 a1 = *(const float4*)(As + kk * 132 + 8 * ty + 4);
            float4 bv = *(const float4*)(Bs + kk * 64 + 4 * tx);
            float ar[8] = {a0.x, a0.y, a0.z, a0.w, a1.x, a1.y, a1.z, a1.w};
            float br[4] = {bv.x, bv.y, bv.z, bv.w};
            #pragma unroll
            for (int i = 0; i < 8; ++i)
                #pragma unroll
                for (int j = 0; j < 4; ++j)
                    acc[i][j] += ar[i] * br[j];
        }
        __syncthreads();
    }
    int plane = tx >> 2;
    int oo4   = 4 * (tx & 3);
    #pragma unroll
    for (int i = 0; i < 8; ++i) {
        int row  = 8 * ty + i;
        int grow = block_row + row;
        if (grow < n) {
            float s = 1.0f / fmaxf(sums[row], 1e-8f);
            ushort4 o;
            o.x = f2bf(acc[i][0] * s); o.y = f2bf(acc[i][1] * s);
            o.z = f2bf(acc[i][2] * s); o.w = f2bf(acc[i][3] * s);
            *(ushort4*)(zb + (long)plane * nstride + (long)grow * 16 + oo4) = o;
        }
    }
}

// ---- CSR SpMM on bf16 planes: 4 lanes/row, 8B gathers, fp32 accumulate ----
__global__ __launch_bounds__(256) void spmm_csr_bf_kernel(
    const u16* __restrict__ in, const u16* __restrict__ addsrc,
    u16* __restrict__ out, const int* __restrict__ rowptr,
    const float2* __restrict__ ecolw, const float* __restrict__ b,
    int relu, int n)
{
    int t = blockIdx.x * blockDim.x + threadIdx.x;
    int r = t >> 2, q = t & 3;
    if (r >= n) return;
    int e0 = rowptr[r], e1 = rowptr[r + 1];
    float a0x=0,a0y=0,a0z=0,a0w=0, a1x=0,a1y=0,a1z=0,a1w=0;
    float a2x=0,a2y=0,a2z=0,a2w=0, a3x=0,a3y=0,a3z=0,a3w=0;
    int e = e0;
    for (; e + 4 <= e1; e += 4) {
        float2 c0 = ecolw[e], c1 = ecolw[e+1], c2 = ecolw[e+2], c3 = ecolw[e+3];
        ushort4 v0 = *((const ushort4*)(in + (long)__float_as_int(c0.x) * 16) + q);
        ushort4 v1 = *((const ushort4*)(in + (long)__float_as_int(c1.x) * 16) + q);
        ushort4 v2 = *((const ushort4*)(in + (long)__float_as_int(c2.x) * 16) + q);
        ushort4 v3 = *((const ushort4*)(in + (long)__float_as_int(c3.x) * 16) + q);
        a0x += c0.y * bf2f(v0.x); a0y += c0.y * bf2f(v0.y); a0z += c0.y * bf2f(v0.z); a0w += c0.y * bf2f(v0.w);
        a1x += c1.y * bf2f(v1.x); a1y += c1.y * bf2f(v1.y); a1z += c1.y * bf2f(v1.z); a1w += c1.y * bf2f(v1.w);
        a2x += c2.y * bf2f(v2.x); a2y += c2.y * bf2f(v2.y); a2z += c2.y * bf2f(v2.z); a2w += c2.y * bf2f(v2.w);
        a3x += c3.y * bf2f(v3.x); a3y += c3.y * bf2f(v3.y); a3z += c3.y * bf2f(v3.z); a3w += c3.y * bf2f(v3.w);
    }
    for (; e < e1; ++e) {
        float2 c0 = ecolw[e];
        ushort4 v0 = *((const ushort4*)(in + (long)__float_as_int(c0.x) * 16) + q);
        a0x += c0.y * bf2f(v0.x); a0y += c0.y * bf2f(v0.y); a0z += c0.y * bf2f(v0.z); a0w += c0.y * bf2f(v0.w);
    }
    float Ax = (a0x+a1x)+(a2x+a3x), Ay = (a0y+a1y)+(a2y+a3y);
    float Az = (a0z+a1z)+(a2z+a3z), Aw = (a0w+a1w)+(a2w+a3w);
    if (addsrc) {
        ushort4 s = *((const ushort4*)(addsrc + (long)r * 16) + q);
        Ax += bf2f(s.x); Ay += bf2f(s.y); Az += bf2f(s.z); Aw += bf2f(s.w);
    }
    if (b) {
        float4 bb = *((const float4*)b + q);
        Ax += bb.x; Ay += bb.y; Az += bb.z; Aw += bb.w;
    }
    if (relu) {
        Ax = fmaxf(Ax, 0.f); Ay = fmaxf(Ay, 0.f);
        Az = fmaxf(Az, 0.f); Aw = fmaxf(Aw, 0.f);
    }
    ushort4 o; o.x = f2bf(Ax); o.y = f2bf(Ay); o.z = f2bf(Az); o.w = f2bf(Aw);
    *((ushort4*)(out + (long)r * 16) + q) = o;
}

// ---- GEMM2 (tiled, bf16 planes in, fp32 out): out = cat(G0..G3) @ W2cat + b2 ----
__global__ __launch_bounds__(256) void gemm2_bf_kernel(
    const u16* __restrict__ zb, const float* __restrict__ W2,
    const float* __restrict__ b2, float* __restrict__ out, int n, int nstride)
{
    __shared__ float As[64 * 132];
    __shared__ float Bs[64 * 64];
    const int t  = threadIdx.x;
    const int tx = t & 15;
    const int ty = t >> 4;
    const int c  = t & 15;
    const int g  = t >> 4;
    const int block_row = blockIdx.x * 128;

    float acc[8][4];
    #pragma unroll
    for (int i = 0; i < 8; ++i)
        #pragma unroll
        for (int j = 0; j < 4; ++j) acc[i][j] = 0.f;

    #pragma unroll
    for (int i = 0; i < 8; ++i) {
        int row  = g + 16 * i;
        int grow = block_row + row;
        float v0 = 0.f, v1 = 0.f, v2 = 0.f, v3 = 0.f;
        if (grow < n) {
            const u16* zp = zb + (long)grow * 16 + c;
            v0 = bf2f(zp[0]);
            v1 = bf2f(zp[(long)nstride]);
            v2 = bf2f(zp[2 * (long)nstride]);
            v3 = bf2f(zp[3 * (long)nstride]);
        }
        As[(c +  0) * 132 + row] = v0;
        As[(c + 16) * 132 + row] = v1;
        As[(c + 32) * 132 + row] = v2;
        As[(c + 48) * 132 + row] = v3;
    }
    #pragma unroll
    for (int i2 = 0; i2 < 4; ++i2) {
        int j = g + 16 * i2;
        float4 wv = *(const float4*)(W2 + j * 64 + 4 * c);
        *(float4*)(Bs + j * 64 + 4 * c) = wv;
    }
    __syncthreads();
    #pragma unroll 4
    for (int kk = 0; kk < 64; ++kk) {
        float4 a0 = *(const float4*)(As + kk * 132 + 8 * ty);
        float4 a1 = *(const float4*)(As + kk * 132 + 8 * ty + 4);
        float4 bv = *(const float4*)(Bs + kk * 64 + 4 * tx);
        float ar[8] = {a0.x, a0.y, a0.z, a0.w, a1.x, a1.y, a1.z, a1.w};
        float br[4] = {bv.x, bv.y, bv.z, bv.w};
        #pragma unroll
        for (int i = 0; i < 8; ++i)
            #pragma unroll
            for (int j = 0; j < 4; ++j)
                acc[i][j] += ar[i] * br[j];
    }
    float4 bias = *(const float4*)(b2 + 4 * tx);
    #pragma unroll
    for (int i = 0; i < 8; ++i) {
        int grow = block_row + 8 * ty + i;
        if (grow < n) {
            float4 o = make_float4(acc[i][0] + bias.x, acc[i][1] + bias.y,
                                   acc[i][2] + bias.z, acc[i][3] + bias.w);
            *(float4*)(out + (long)grow * 64 + 4 * tx) = o;
        }
    }
}

// ================= fp32 fallback path (small workspace or huge n) =================
__global__ void deg_kernel(const int* __restrict__ dst, float* __restrict__ deg, int E) {
    int e = blockIdx.x * blockDim.x + threadIdx.x;
    if (e < E) atomicAdd(&deg[dst[e]], 1.0f);
}
__global__ void disf_kernel(float* __restrict__ deg, int n) {
    int i = blockIdx.x * blockDim.x + threadIdx.x;
    if (i < n) {
        float d = deg[i];
        deg[i] = (d > 0.0f) ? rsqrtf(d) : 0.0f;
    }
}
__global__ __launch_bounds__(256) void gemm1_f32_kernel(
    const float* __restrict__ x, const float* __restrict__ W1,
    float* __restrict__ z, int n, int nstride)
{
    __shared__ float As[64 * 132];
    __shared__ float Bs[64 * 64];
    __shared__ float sums[128];
    const int t  = threadIdx.x;
    const int tx = t & 15;
    const int ty = t >> 4;
    const int c  = t & 15;
    const int g  = t >> 4;
    const int block_row = blockIdx.x * 128;
    float acc[8][4];
    #pragma unroll
    for (int i = 0; i < 8; ++i)
        #pragma unroll
        for (int j = 0; j < 4; ++j) acc[i][j] = 0.f;
    for (int kp = 0; kp < 2; ++kp) {
        #pragma unroll
        for (int i = 0; i < 8; ++i) {
            int row  = g + 16 * i;
            int grow = block_row + row;
            float v0 = 0.f, v1 = 0.f, v2 = 0.f, v3 = 0.f;
            if (grow < n) {
                const float* xp = x + (long)grow * 128 + kp * 64 + c;
                v0 = xp[0]; v1 = xp[16]; v2 = xp[32]; v3 = xp[48];
            }
            As[(c +  0) * 132 + row] = v0;
            As[(c + 16) * 132 + row] = v1;
            As[(c + 32) * 132 + row] = v2;
            As[(c + 48) * 132 + row] = v3;
            float red = (v0 + v1) + (v2 + v3);
            #pragma unroll
            for (int off = 8; off > 0; off >>= 1) red += __shfl_down(red, off, 16);
            if (c == 0) { if (kp == 0) sums[row] = red; else sums[row] += red; }
        }
        #pragma unroll
        for (int i2 = 0; i2 < 4; ++i2) {
            int kk = g + 16 * i2;
            int kglob = kp * 64 + kk;
            float4 wv = *(const float4*)(W1 + (c >> 2) * 2048 + kglob * 16 + 4 * (c & 3));
            *(float4*)(Bs + kk * 64 + 4 * c) = wv;
        }
        __syncthreads();
        #pragma unroll 4
        for (int kk = 0; kk < 64; ++kk) {
            float4 a0 = *(const float4*)(As + kk * 132 + 8 * ty);
            float4 a1 = *(const float4*)(As + kk * 132 + 8 * ty + 4);
            float4 bv = *(const float4*)(Bs + kk * 64 + 4 * tx);
            float ar[8] = {a0.x, a0.y, a0.z, a0.w, a1.x, a1.y, a1.z, a1.w};
            float br[4] = {bv.x, bv.y, bv.z, bv.w};
            #pragma unroll
            for (int i = 0; i < 8; ++i)
                #pragma unroll
                for (int j = 0; j < 4; ++j)
                    acc[i][j] += ar[i] * br[j];
        }
        __syncthreads();
    }
    int plane = tx >> 2;
    int oo4   = 4 * (tx & 3);
    #pragma unroll
    for (int i = 0; i < 8; ++i) {
        int row  = 8 * ty + i;
        int grow = block_row + row;
        if (grow < n) {
            float s = 1.0f / fmaxf(sums[row], 1e-8f);
            float4 o = make_float4(acc[i][0] * s, acc[i][1] * s, acc[i][2] * s, acc[i][3] * s);
            *(float4*)(z + (long)plane * nstride + (long)grow * 16 + oo4) = o;
        }
    }
}
__global__ __launch_bounds__(256) void spmm_atomic_kernel(
    const float* __restrict__ in, float* __restrict__ out,
    const int* __restrict__ src, const int* __restrict__ dst,
    const float* __restrict__ dis, int E)
{
    int t = blockIdx.x * blockDim.x + threadIdx.x;
    int e = t >> 4, f = t & 15;
    if (e < E) {
        int s = src[e], d = dst[e];
        atomicAdd(&out[d * 16 + f], dis[s] * dis[d] * in[s * 16 + f]);
    }
}
__global__ void bias_relu_kernel(float* __restrict__ z0, const float* __restrict__ b, int total) {
    int i = blockIdx.x * blockDim.x + threadIdx.x;
    if (i < total) {
        float v = z0[i] + b[i & 15];
        z0[i] = v > 0.0f ? v : 0.0f;
    }
}
__global__ __launch_bounds__(256) void gemm2_f32_kernel(
    const float* __restrict__ z, const float* __restrict__ W2,
    const float* __restrict__ b2, float* __restrict__ out, int n, int nstride)
{
    __shared__ float As[64 * 132];
    __shared__ float Bs[64 * 64];
    const int t  = threadIdx.x;
    const int tx = t & 15;
    const int ty = t >> 4;
    const int c  = t & 15;
    const int g  = t >> 4;
    const int block_row = blockIdx.x * 128;
    float acc[8][4];
    #pragma unroll
    for (int i = 0; i < 8; ++i)
        #pragma unroll
        for (int j = 0; j < 4; ++j) acc[i][j] = 0.f;
    #pragma unroll
    for (int i = 0; i < 8; ++i) {
        int row  = g + 16 * i;
        int grow = block_row + row;
        float v0 = 0.f, v1 = 0.f, v2 = 0.f, v3 = 0.f;
        if (grow < n) {
            const float* zp = z + (long)grow * 16 + c;
            v0 = zp[0];
            v1 = zp[(long)nstride];
            v2 = zp[2 * (long)nstride];
            v3 = zp[3 * (long)nstride];
        }
        As[(c +  0) * 132 + row] = v0;
        As[(c + 16) * 132 + row] = v1;
        As[(c + 32) * 132 + row] = v2;
        As[(c + 48) * 132 + row] = v3;
    }
    #pragma unroll
    for (int i2 = 0; i2 < 4; ++i2) {
        int j = g + 16 * i2;
        float4 wv = *(const float4*)(W2 + j * 64 + 4 * c);
        *(float4*)(Bs + j * 64 + 4 * c) = wv;
    }
    __syncthreads();
    #pragma unroll 4
    for (int kk = 0; kk < 64; ++kk) {
        float4 a0 = *(const float4*)(As + kk * 132 + 8 * ty);
        float4 a1 = *(const float4*)(As + kk * 132 + 8 * ty + 4);
        float4 bv = *(const float4*)(Bs + kk * 64 + 4 * tx);
        float ar[8] = {a0.x, a0.y, a0.z, a0.w, a1.x, a1.y, a1.z, a1.w};
        float br[4] = {bv.x, bv.y, bv.z, bv.w};
        #pragma unroll
        for (int i = 0; i < 8; ++i)
            #pragma unroll
            for (int j = 0; j < 4; ++j)
                acc[i][j] += ar[i] * br[j];
    }
    float4 bias = *(const float4*)(b2 + 4 * tx);
    #pragma unroll
    for (int i = 0; i < 8; ++i) {
        int grow = block_row + 8 * ty + i;
        if (grow < n) {
            float4 o = make_float4(acc[i][0] + bias.x, acc[i][1] + bias.y,
                                   acc[i][2] + bias.z, acc[i][3] + bias.w);
            *(float4*)(out + (long)grow * 64 + 4 * tx) = o;
        }
    }
}

static inline size_t align16(size_t v) { return (v + 15) & ~(size_t)15; }

extern "C" void kernel_launch(void* const* d_in, const int* in_sizes, int n_in,
                              void* d_out, int out_size, void* d_ws, size_t ws_size,
                              hipStream_t stream) {
    const float* x   = (const float*)d_in[0];
    const int*   ei  = (const int*)d_in[1];
    const float* W1  = (const float*)d_in[2];
    const float* b1  = (const float*)d_in[3];
    const float* W2  = (const float*)d_in[4];
    const float* bb2 = (const float*)d_in[5];
    float* out = (float*)d_out;

    const int n  = in_sizes[0] / 128;   // 50000
    const int E  = in_sizes[1] / 2;     // 800000
    const int NS = n * 16;

    const int* srcp = ei;
    const int* dstp = ei + E;

    const int nbuck = (n + BKT_SIZE - 1) >> BKT_SHIFT;         // 391
    const int nbA   = (E + CHUNK - 1) / CHUNK;                 // 391
    const int m     = nbuck * nbA;                             // ~153k
    const int nbS   = (m + 255) / 256;                         // scan blocks

    char* wsb = (char*)d_ws;
    // bytes: hist[m] | hofs[m+1] | bsum[1024] | rowptr[n+1] | dis[n] | zb[4*NS u16] | bucketed[E i2] | ecolw[E f2]
    int*   hist   = (int*)wsb;
    int*   hofs   = (int*)(wsb + (size_t)4 * m);
    int*   bsum   = (int*)(wsb + (size_t)4 * (2 * m + 1));
    int*   rowptr = (int*)(wsb + (size_t)4 * (2 * m + 1 + 1024));
    float* dis    = (float*)(wsb + (size_t)4 * (2 * m + 1 + 1024 + n + 1));
    size_t zoffb  = align16((size_t)4 * (2 * m + 1 + 1024 + 2 * n + 1));
    u16*   zb     = (u16*)(wsb + zoffb);
    size_t bkoff  = align16(zoffb + (size_t)2 * 4 * NS);
    int2*  bucketed = (int2*)(wsb + bkoff);
    size_t ecooff = align16(bkoff + (size_t)8 * E);
    float2* ecolw = (float2*)(wsb + ecooff);
    size_t need   = ecooff + (size_t)8 * E;

    int gemm_blocks = (n + 127) / 128;

    if (ws_size >= need && nbuck <= 512 && nbS <= 256 * 1024) {
        // ---------- LDS-bucket CSR build (zero global atomics) ----------
        hist_kernel<<<nbA, 256, 0, stream>>>(dstp, hist, E, nbA, nbuck);
        if (nbS <= 1024) {
            scanA_kernel<<<nbS, 256, 0, stream>>>(hist, hofs, bsum, m);
            scanB_kernel<<<1, 1024, 0, stream>>>(bsum, nbS);
            scanC_kernel<<<nbS, 256, 0, stream>>>(hofs, bsum, m);
        }
        bucket_scatter_kernel<<<nbA, 256, 0, stream>>>(srcp, dstp, hofs, bucketed, E, nbA, nbuck);
        csr_finalize_kernel<<<nbuck, 256, 0, stream>>>(bucketed, hofs, rowptr, dis, ecolw, E, nbA, nbuck, n);
        weight_kernel<<<(E + 255) / 256, 256, 0, stream>>>(ecolw, dis, E);

        gemm1_bf_kernel<<<gemm_blocks, 256, 0, stream>>>(x, W1, zb, n, NS);

        int sb = (4 * n + 255) / 256;
        // layer-1 Horner
        spmm_csr_bf_kernel<<<sb, 256, 0, stream>>>(zb + 3 * NS, zb + 2 * NS, zb + 2 * NS, rowptr, ecolw, nullptr, 0, n);
        spmm_csr_bf_kernel<<<sb, 256, 0, stream>>>(zb + 2 * NS, zb + 1 * NS, zb + 1 * NS, rowptr, ecolw, nullptr, 0, n);
        spmm_csr_bf_kernel<<<sb, 256, 0, stream>>>(zb + 1 * NS, zb,          zb,          rowptr, ecolw, b1,      1, n);
        // layer-2 hops
        spmm_csr_bf_kernel<<<sb, 256, 0, stream>>>(zb,          nullptr, zb + 1 * NS, rowptr, ecolw, nullptr, 0, n);
        spmm_csr_bf_kernel<<<sb, 256, 0, stream>>>(zb + 1 * NS, nullptr, zb + 2 * NS, rowptr, ecolw, nullptr, 0, n);
        spmm_csr_bf_kernel<<<sb, 256, 0, stream>>>(zb + 2 * NS, nullptr, zb + 3 * NS, rowptr, ecolw, nullptr, 0, n);

        gemm2_bf_kernel<<<gemm_blocks, 256, 0, stream>>>(zb, W2, bb2, out, n, NS);
    } else {
        // ---------- fp32 atomic fallback ----------
        float* ws = (float*)d_ws;
        float* dis2 = ws;
        size_t z2off = ((size_t)n + 3) & ~(size_t)3;
        float* z2 = ws + z2off;
        hipMemsetAsync(dis2, 0, n * sizeof(float), stream);
        deg_kernel<<<(E + 255) / 256, 256, 0, stream>>>(dstp, dis2, E);
        disf_kernel<<<(n + 255) / 256, 256, 0, stream>>>(dis2, n);
        gemm1_f32_kernel<<<gemm_blocks, 256, 0, stream>>>(x, W1, z2, n, NS);
        int sb = (16 * E + 255) / 256;
        spmm_atomic_kernel<<<sb, 256, 0, stream>>>(z2 + 3 * NS, z2 + 2 * NS, srcp, dstp, dis2, E);
        spmm_atomic_kernel<<<sb, 256, 0, stream>>>(z2 + 2 * NS, z2 + 1 * NS, srcp, dstp, dis2, E);
        spmm_atomic_kernel<<<sb, 256, 0, stream>>>(z2 + 1 * NS, z2,          srcp, dstp, dis2, E);
        bias_relu_kernel<<<(NS + 255) / 256, 256, 0, stream>>>(z2, b1, NS);
        hipMemsetAsync(z2 + NS, 0, (size_t)3 * NS * sizeof(float), stream);
        spmm_atomic_kernel<<<sb, 256, 0, stream>>>(z2,          z2 + NS,     srcp, dstp, dis2, E);
        spmm_atomic_kernel<<<sb, 256, 0, stream>>>(z2 + NS,     z2 + 2 * NS, srcp, dstp, dis2, E);
        spmm_atomic_kernel<<<sb, 256, 0, stream>>>(z2 + 2 * NS, z2 + 3 * NS, srcp, dstp, dis2, E);
        gemm2_f32_kernel<<<gemm_blocks, 256, 0, stream>>>(z2, W2, bb2, out, n, NS);
    }
}